// Round 1
// baseline (3882.742 us; speedup 1.0000x reference)
//
#include <hip/hip_runtime.h>
#include <math.h>

#define DIMN   200
#define NNODES 100000
#define NREL   500
#define NEDGES 200000

// ---------------- l2norm: one wave (64 lanes) per row of DIMN=200 ----------------
__launch_bounds__(256)
__global__ void l2norm_rows(const float* __restrict__ in, float* __restrict__ out, int nrows)
{
    int wave = (int)((blockIdx.x * blockDim.x + threadIdx.x) >> 6);
    int lane = threadIdx.x & 63;
    if (wave >= nrows) return;
    const float* row = in + (size_t)wave * DIMN;
    float v0 = row[lane];
    float v1 = row[lane + 64];
    float v2 = row[lane + 128];                       // 128..191 < 200, always valid
    float v3 = (lane < 8) ? row[lane + 192] : 0.0f;   // 192..199
    float ss = v0*v0 + v1*v1 + v2*v2 + v3*v3;
    #pragma unroll
    for (int off = 32; off; off >>= 1) ss += __shfl_xor(ss, off, 64);
    float s = 1.0f / fmaxf(sqrtf(ss), 1e-12f);
    float* orow = out + (size_t)wave * DIMN;
    orow[lane]       = v0 * s;
    orow[lane + 64]  = v1 * s;
    orow[lane + 128] = v2 * s;
    if (lane < 8) orow[lane + 192] = v3 * s;
}

// ------------- gate blend + l2norm fused: h_new = l2norm(g*cur + (1-g)*h) -------------
__launch_bounds__(256)
__global__ void gate_combine(const float* __restrict__ gate, const float* __restrict__ cur,
                             const float* __restrict__ h, float* __restrict__ out, int nrows)
{
    int wave = (int)((blockIdx.x * blockDim.x + threadIdx.x) >> 6);
    int lane = threadIdx.x & 63;
    if (wave >= nrows) return;
    size_t base = (size_t)wave * DIMN;
    float v[4];
    #pragma unroll
    for (int it = 0; it < 4; ++it) {
        int j = lane + 64 * it;
        if (j < DIMN) {
            float g = gate[base + j];
            v[it] = g * cur[base + j] + (1.0f - g) * h[base + j];
        } else v[it] = 0.0f;
    }
    float ss = v[0]*v[0] + v[1]*v[1] + v[2]*v[2] + v[3]*v[3];
    #pragma unroll
    for (int off = 32; off; off >>= 1) ss += __shfl_xor(ss, off, 64);
    float s = 1.0f / fmaxf(sqrtf(ss), 1e-12f);
    #pragma unroll
    for (int it = 0; it < 4; ++it) {
        int j = lane + 64 * it;
        if (j < DIMN) out[base + j] = v[it] * s;
    }
}

// ------------- edge scatter: one wave per edge; agg[dst] += HW[src] + RW[rel] -------------
__launch_bounds__(256)
__global__ void edge_scatter(const int* __restrict__ edges, const float* __restrict__ HW,
                             const float* __restrict__ RW, float* __restrict__ agg,
                             float* __restrict__ deg, int nedges, int addDeg)
{
    int wave = (int)((blockIdx.x * blockDim.x + threadIdx.x) >> 6);
    int lane = threadIdx.x & 63;
    if (wave >= nedges) return;
    int s  = edges[wave * 3 + 0];
    int rl = edges[wave * 3 + 1];
    int d  = edges[wave * 3 + 2];
    const float* hs = HW + (size_t)s  * DIMN;
    const float* rr = RW + (size_t)rl * DIMN;
    float*       ad = agg + (size_t)d * DIMN;
    #pragma unroll
    for (int it = 0; it < 4; ++it) {
        int j = lane + 64 * it;
        if (j < DIMN) atomicAdd(&ad[j], hs[j] + rr[j]);
    }
    if (addDeg && lane == 0) atomicAdd(&deg[d], 1.0f);
}

// ------------- fp32 GEMM: Out[M x 200] = In[M x 200] @ W[200 x 200] (+ epilogue) -------------
// MODE 0: Out = In@W
// MODE 1: Out = Agg/max(Deg,1) + In@W
// MODE 2: Out = sigmoid(In@W + Bias)
template<int MODE>
__launch_bounds__(256)
__global__ void gemm200(const float* __restrict__ In, const float* __restrict__ W,
                        float* __restrict__ Out, int M,
                        const float* __restrict__ Agg, const float* __restrict__ Deg,
                        const float* __restrict__ Bias)
{
    constexpr int BM = 64, BN = 64, BK = 8;
    __shared__ float As[BK][BM];   // transposed: As[k][m]
    __shared__ float Bs[BK][BN];   // Bs[k][n]
    const int tid = threadIdx.x;
    const int bm = blockIdx.x * BM;
    const int bn = blockIdx.y * BN;
    const int tx = tid & 15, ty = tid >> 4;
    const int r0 = ty * 4, c0 = tx * 4;
    float acc[4][4] = {};

    const int la_r = tid >> 2;          // 0..63 row within tile
    const int la_k = (tid & 3) * 2;     // 0,2,4,6
    const int lb_k = tid >> 5;          // 0..7
    const int lb_n = (tid & 31) * 2;    // 0..62 step 2
    const int gr = bm + la_r;

    for (int k0 = 0; k0 < DIMN; k0 += BK) {
        float a0 = 0.f, a1 = 0.f, b0 = 0.f, b1 = 0.f;
        if (gr < M) {
            const float* p = In + (size_t)gr * DIMN + k0 + la_k;
            a0 = p[0]; a1 = p[1];
        }
        {
            int gc = bn + lb_n;
            const float* p = W + (size_t)(k0 + lb_k) * DIMN + gc;
            if (gc < DIMN)     b0 = p[0];
            if (gc + 1 < DIMN) b1 = p[1];
        }
        __syncthreads();
        As[la_k][la_r]     = a0;
        As[la_k + 1][la_r] = a1;
        Bs[lb_k][lb_n]     = b0;
        Bs[lb_k][lb_n + 1] = b1;
        __syncthreads();
        #pragma unroll
        for (int kk = 0; kk < BK; ++kk) {
            float4 av = *(const float4*)&As[kk][r0];
            float4 bv = *(const float4*)&Bs[kk][c0];
            float a[4] = {av.x, av.y, av.z, av.w};
            float b[4] = {bv.x, bv.y, bv.z, bv.w};
            #pragma unroll
            for (int i = 0; i < 4; ++i)
                #pragma unroll
                for (int j = 0; j < 4; ++j)
                    acc[i][j] = fmaf(a[i], b[j], acc[i][j]);
        }
    }

    #pragma unroll
    for (int i = 0; i < 4; ++i) {
        int row = bm + r0 + i;
        if (row >= M) continue;
        float rdeg = 0.0f;
        if (MODE == 1) rdeg = 1.0f / fmaxf(Deg[row], 1.0f);
        #pragma unroll
        for (int j = 0; j < 4; ++j) {
            int col = bn + c0 + j;
            if (col >= DIMN) continue;
            float v = acc[i][j];
            if (MODE == 1) v += Agg[(size_t)row * DIMN + col] * rdeg;
            if (MODE == 2) { v += Bias[col]; v = 1.0f / (1.0f + __expf(-v)); }
            Out[(size_t)row * DIMN + col] = v;
        }
    }
}

extern "C" void kernel_launch(void* const* d_in, const int* in_sizes, int n_in,
                              void* d_out, int out_size, void* d_ws, size_t ws_size,
                              hipStream_t stream)
{
    const int*   edges = (const int*)  d_in[0];
    const float* ent   = (const float*)d_in[1];
    const float* relE  = (const float*)d_in[2];
    const float* Wm1   = (const float*)d_in[3];
    const float* Wl1   = (const float*)d_in[4];
    const float* Wm2   = (const float*)d_in[5];
    const float* Wl2   = (const float*)d_in[6];
    const float* Wtg   = (const float*)d_in[7];
    const float* bias  = (const float*)d_in[8];
    float* Dout = (float*)d_out;   // also used as the 4th big scratch buffer

    const size_t NM = (size_t)NNODES * DIMN;
    float* A   = (float*)d_ws;                      // h
    float* B   = A + NM;                            // HW1 / out1
    float* C   = B + NM;                            // agg / gate
    float* Rn  = C + NM;                            // normalized relations
    float* RWb = Rn + (size_t)NREL * DIMN;          // r @ W_msg
    float* deg = RWb + (size_t)NREL * DIMN;         // degrees

    dim3 blk(256);
    dim3 ngrid((NNODES + 3) / 4);
    dim3 ggrid((NNODES + 63) / 64, (DIMN + 63) / 64);
    dim3 rgrid((NREL + 63) / 64, (DIMN + 63) / 64);
    dim3 egrid((NEDGES + 3) / 4);

    l2norm_rows<<<ngrid, blk, 0, stream>>>(ent, A, NNODES);
    l2norm_rows<<<dim3((NREL + 3) / 4), blk, 0, stream>>>(relE, Rn, NREL);

    for (int t = 0; t < 3; ++t) {
        const int* ed = edges + (size_t)t * NEDGES * 3;
        // ---- layer 1: in = A, out -> B ----
        gemm200<0><<<ggrid, blk, 0, stream>>>(A, Wm1, B, NNODES, nullptr, nullptr, nullptr);
        gemm200<0><<<rgrid, blk, 0, stream>>>(Rn, Wm1, RWb, NREL, nullptr, nullptr, nullptr);
        hipMemsetAsync(C, 0, NM * sizeof(float), stream);
        hipMemsetAsync(deg, 0, NNODES * sizeof(float), stream);
        edge_scatter<<<egrid, blk, 0, stream>>>(ed, B, RWb, C, deg, NEDGES, 1);
        gemm200<1><<<ggrid, blk, 0, stream>>>(A, Wl1, B, NNODES, C, deg, nullptr);
        // ---- layer 2: in = B, out -> Dout ----
        gemm200<0><<<ggrid, blk, 0, stream>>>(B, Wm2, Dout, NNODES, nullptr, nullptr, nullptr);
        gemm200<0><<<rgrid, blk, 0, stream>>>(Rn, Wm2, RWb, NREL, nullptr, nullptr, nullptr);
        hipMemsetAsync(C, 0, NM * sizeof(float), stream);
        edge_scatter<<<egrid, blk, 0, stream>>>(ed, Dout, RWb, C, deg, NEDGES, 0);
        gemm200<1><<<ggrid, blk, 0, stream>>>(B, Wl2, Dout, NNODES, C, deg, nullptr);
        // ---- l2norm(cur) in place ----
        l2norm_rows<<<ngrid, blk, 0, stream>>>(Dout, Dout, NNODES);
        // ---- gate = sigmoid(h @ Wtg + bias) -> C ----
        gemm200<2><<<ggrid, blk, 0, stream>>>(A, Wtg, C, NNODES, nullptr, nullptr, bias);
        // ---- h = l2norm(gate*cur + (1-gate)*h) ----
        float* outp = (t == 2) ? Dout : A;
        gate_combine<<<ngrid, blk, 0, stream>>>(C, Dout, A, outp, NNODES);
    }
}

// Round 2
// 2525.211 us; speedup vs baseline: 1.5376x; 1.5376x over previous
//
#include <hip/hip_runtime.h>
#include <math.h>

#define DIMN   200
#define NNODES 100000
#define NREL   500
#define NEDGES 200000
#define KSTEPS 7            // K padded 200 -> 224 = 7*32
#define NB16   16           // N padded 200 -> 256 = 16 tiles of 16
#define WPK_ELEMS (KSTEPS * NB16 * 64 * 8)   // 57344 bf16 per weight

typedef float v4f __attribute__((ext_vector_type(4)));
typedef __bf16 v8bf __attribute__((ext_vector_type(8)));

// ---------------- l2norm: one wave per row ----------------
__launch_bounds__(256)
__global__ void l2norm_rows(const float* __restrict__ in, float* __restrict__ out, int nrows)
{
    int wave = (int)((blockIdx.x * blockDim.x + threadIdx.x) >> 6);
    int lane = threadIdx.x & 63;
    if (wave >= nrows) return;
    const float* row = in + (size_t)wave * DIMN;
    float v0 = row[lane];
    float v1 = row[lane + 64];
    float v2 = row[lane + 128];
    float v3 = (lane < 8) ? row[lane + 192] : 0.0f;
    float ss = v0*v0 + v1*v1 + v2*v2 + v3*v3;
    #pragma unroll
    for (int off = 32; off; off >>= 1) ss += __shfl_xor(ss, off, 64);
    float s = 1.0f / fmaxf(sqrtf(ss), 1e-12f);
    float* orow = out + (size_t)wave * DIMN;
    orow[lane]       = v0 * s;
    orow[lane + 64]  = v1 * s;
    orow[lane + 128] = v2 * s;
    if (lane < 8) orow[lane + 192] = v3 * s;
}

// ---------------- edge scatter (unchanged; fp32 atomics) ----------------
__launch_bounds__(256)
__global__ void edge_scatter(const int* __restrict__ edges, const float* __restrict__ HW,
                             const float* __restrict__ RW, float* __restrict__ agg,
                             float* __restrict__ deg, int nedges, int addDeg)
{
    int wave = (int)((blockIdx.x * blockDim.x + threadIdx.x) >> 6);
    int lane = threadIdx.x & 63;
    if (wave >= nedges) return;
    int s  = edges[wave * 3 + 0];
    int rl = edges[wave * 3 + 1];
    int d  = edges[wave * 3 + 2];
    const float* hs = HW + (size_t)s  * DIMN;
    const float* rr = RW + (size_t)rl * DIMN;
    float*       ad = agg + (size_t)d * DIMN;
    #pragma unroll
    for (int it = 0; it < 4; ++it) {
        int j = lane + 64 * it;
        if (j < DIMN) atomicAdd(&ad[j], hs[j] + rr[j]);
    }
    if (addDeg && lane == 0) atomicAdd(&deg[d], 1.0f);
}

// ---------------- weight pack: fp32 W[200x200] -> bf16 MFMA-B-fragment-linear ----------------
// chunk c in [0,7168): s = c>>10, nb16 = (c&1023)>>6, lane = c&63; elem j in [0,8):
//   k = s*32 + (lane>>4)*8 + j ; n = nb16*16 + (lane&15) ; zero-padded past 200.
__launch_bounds__(256)
__global__ void pack_w(const float* __restrict__ W0, const float* __restrict__ W1,
                       const float* __restrict__ W2, const float* __restrict__ W3,
                       const float* __restrict__ W4, __bf16* __restrict__ out)
{
    int id = blockIdx.x * 256 + threadIdx.x;
    const int nchunk = KSTEPS * NB16 * 64;        // 7168
    if (id >= 5 * nchunk) return;
    int wi = id / nchunk;
    int c  = id % nchunk;
    const float* W = wi == 0 ? W0 : wi == 1 ? W1 : wi == 2 ? W2 : wi == 3 ? W3 : W4;
    int s    = c >> 10;
    int nb   = (c & 1023) >> 6;
    int lane = c & 63;
    int kbase = s * 32 + (lane >> 4) * 8;
    int n     = nb * 16 + (lane & 15);
    __bf16* dst = out + (size_t)wi * WPK_ELEMS + (size_t)c * 8;
    #pragma unroll
    for (int j = 0; j < 8; ++j) {
        int k = kbase + j;
        float v = (k < DIMN && n < DIMN) ? W[k * DIMN + n] : 0.0f;
        dst[j] = (__bf16)v;
    }
}

// ---------------- MFMA GEMM: Out[M x 200] = In[M x 200] @ W + epilogue ----------------
// Block: 256 thr (4 waves), BM=64, BN=256 (full padded N). Wave w covers cols w*64..w*64+63.
// EPI 0: Out = acc
// EPI 1: Out = acc + Agg/max(Deg,1)
// EPI 2: Out = l2norm_row(acc + Agg/max(Deg,1))
// EPI 3: g = sigmoid(acc + Bias); Out = l2norm_row(g*Cur + (1-g)*In)
template<int EPI>
__launch_bounds__(256, 3)
__global__ void gemm_mfma(const float* __restrict__ In, const __bf16* __restrict__ Wpk,
                          float* __restrict__ Out, int M,
                          const float* __restrict__ Agg, const float* __restrict__ Deg,
                          const float* __restrict__ Bias, const float* __restrict__ Cur)
{
    const int tid  = threadIdx.x;
    const int w    = tid >> 6;
    const int lane = tid & 63;
    const int rlo  = lane & 15;     // A row / D col within 16-tile
    const int g    = lane >> 4;     // k-octet / D row-quad
    const int bm   = blockIdx.x * 64;

    __shared__ float rsq[64][4];

    v4f acc[4][4];
    #pragma unroll
    for (int mi = 0; mi < 4; ++mi)
        #pragma unroll
        for (int ni = 0; ni < 4; ++ni)
            acc[mi][ni] = (v4f){0.f, 0.f, 0.f, 0.f};

    for (int s = 0; s < KSTEPS; ++s) {
        v8bf bv[4];
        #pragma unroll
        for (int ni = 0; ni < 4; ++ni) {
            int nb = w * 4 + ni;
            bv[ni] = *(const v8bf*)(Wpk + ((size_t)(s * NB16 + nb) * 64 + lane) * 8);
        }
        #pragma unroll
        for (int mi = 0; mi < 4; ++mi) {
            int row = bm + mi * 16 + rlo;
            int k0  = s * 32 + g * 8;
            float4 fa = {0.f, 0.f, 0.f, 0.f}, fb = {0.f, 0.f, 0.f, 0.f};
            if (row < M && k0 < DIMN) {
                const float4* p = (const float4*)(In + (size_t)row * DIMN + k0);
                fa = p[0];
                fb = p[1];
            }
            v8bf a;
            a[0] = (__bf16)fa.x; a[1] = (__bf16)fa.y; a[2] = (__bf16)fa.z; a[3] = (__bf16)fa.w;
            a[4] = (__bf16)fb.x; a[5] = (__bf16)fb.y; a[6] = (__bf16)fb.z; a[7] = (__bf16)fb.w;
            #pragma unroll
            for (int ni = 0; ni < 4; ++ni)
                acc[mi][ni] = __builtin_amdgcn_mfma_f32_16x16x32_bf16(a, bv[ni], acc[mi][ni], 0, 0, 0);
        }
    }

    // ---- epilogue ----
    // D layout: row_local = mi*16 + g*4 + reg ; col = w*64 + ni*16 + rlo
    if (EPI == 0 || EPI == 1) {
        #pragma unroll
        for (int mi = 0; mi < 4; ++mi) {
            #pragma unroll
            for (int reg = 0; reg < 4; ++reg) {
                int r = bm + mi * 16 + g * 4 + reg;
                if (r >= M) continue;
                float rdeg = (EPI == 1) ? 1.0f / fmaxf(Deg[r], 1.0f) : 0.0f;
                #pragma unroll
                for (int ni = 0; ni < 4; ++ni) {
                    int c = w * 64 + ni * 16 + rlo;
                    if (c >= DIMN) continue;
                    float v = acc[mi][ni][reg];
                    if (EPI == 1) v += Agg[(size_t)r * DIMN + c] * rdeg;
                    Out[(size_t)r * DIMN + c] = v;
                }
            }
        }
    } else {
        // transform acc in place
        #pragma unroll
        for (int mi = 0; mi < 4; ++mi) {
            #pragma unroll
            for (int reg = 0; reg < 4; ++reg) {
                int r = bm + mi * 16 + g * 4 + reg;
                float rdeg = (EPI == 2 && r < M) ? 1.0f / fmaxf(Deg[r], 1.0f) : 0.0f;
                #pragma unroll
                for (int ni = 0; ni < 4; ++ni) {
                    int c = w * 64 + ni * 16 + rlo;
                    float v = 0.0f;
                    if (r < M && c < DIMN) {
                        if (EPI == 2) {
                            v = acc[mi][ni][reg] + Agg[(size_t)r * DIMN + c] * rdeg;
                        } else { // EPI == 3
                            float gl = acc[mi][ni][reg] + Bias[c];
                            float gg = 1.0f / (1.0f + __expf(-gl));
                            v = gg * Cur[(size_t)r * DIMN + c] + (1.0f - gg) * In[(size_t)r * DIMN + c];
                        }
                    }
                    acc[mi][ni][reg] = v;
                }
            }
        }
        // per-row sum of squares: reduce over the 16 lanes (rlo) then across 4 waves via LDS
        #pragma unroll
        for (int mi = 0; mi < 4; ++mi) {
            #pragma unroll
            for (int reg = 0; reg < 4; ++reg) {
                float ss = 0.0f;
                #pragma unroll
                for (int ni = 0; ni < 4; ++ni) ss += acc[mi][ni][reg] * acc[mi][ni][reg];
                ss += __shfl_xor(ss, 1, 64);
                ss += __shfl_xor(ss, 2, 64);
                ss += __shfl_xor(ss, 4, 64);
                ss += __shfl_xor(ss, 8, 64);
                if (rlo == 0) rsq[mi * 16 + g * 4 + reg][w] = ss;
            }
        }
        __syncthreads();
        #pragma unroll
        for (int mi = 0; mi < 4; ++mi) {
            #pragma unroll
            for (int reg = 0; reg < 4; ++reg) {
                int rl = mi * 16 + g * 4 + reg;
                int r  = bm + rl;
                float tot = rsq[rl][0] + rsq[rl][1] + rsq[rl][2] + rsq[rl][3];
                float sc  = 1.0f / fmaxf(sqrtf(tot), 1e-12f);
                if (r >= M) continue;
                #pragma unroll
                for (int ni = 0; ni < 4; ++ni) {
                    int c = w * 64 + ni * 16 + rlo;
                    if (c >= DIMN) continue;
                    Out[(size_t)r * DIMN + c] = acc[mi][ni][reg] * sc;
                }
            }
        }
    }
}

extern "C" void kernel_launch(void* const* d_in, const int* in_sizes, int n_in,
                              void* d_out, int out_size, void* d_ws, size_t ws_size,
                              hipStream_t stream)
{
    const int*   edges = (const int*)  d_in[0];
    const float* ent   = (const float*)d_in[1];
    const float* relE  = (const float*)d_in[2];
    const float* Wm1   = (const float*)d_in[3];
    const float* Wl1   = (const float*)d_in[4];
    const float* Wm2   = (const float*)d_in[5];
    const float* Wl2   = (const float*)d_in[6];
    const float* Wtg   = (const float*)d_in[7];
    const float* bias  = (const float*)d_in[8];
    float* Dout = (float*)d_out;          // also serves as 'cur' buffer

    const size_t NM = (size_t)NNODES * DIMN;
    float* A   = (float*)d_ws;                       // h (fp32)
    float* B   = A + NM;                             // layer-1 intermediates
    float* C   = B + NM;                             // agg
    float* Rn  = C + NM;                             // normalized relations
    float* RW  = Rn + (size_t)NREL * DIMN;           // r @ W_msg
    float* deg = RW + (size_t)NREL * DIMN;           // degrees
    __bf16* Wpk = (__bf16*)(deg + NNODES);           // 5 packed weights
    __bf16* pWm1 = Wpk + 0 * (size_t)WPK_ELEMS;
    __bf16* pWl1 = Wpk + 1 * (size_t)WPK_ELEMS;
    __bf16* pWm2 = Wpk + 2 * (size_t)WPK_ELEMS;
    __bf16* pWl2 = Wpk + 3 * (size_t)WPK_ELEMS;
    __bf16* pWtg = Wpk + 4 * (size_t)WPK_ELEMS;

    dim3 blk(256);
    const int GN = (NNODES + 63) / 64;     // 1563
    const int GR = (NREL + 63) / 64;       // 8
    dim3 ngrid((NNODES + 3) / 4);
    dim3 egrid((NEDGES + 3) / 4);

    // one-time per launch: pack weights to bf16 fragment layout
    pack_w<<<dim3((5 * KSTEPS * NB16 * 64 + 255) / 256), blk, 0, stream>>>(Wm1, Wl1, Wm2, Wl2, Wtg, Wpk);

    l2norm_rows<<<ngrid, blk, 0, stream>>>(ent, A, NNODES);
    l2norm_rows<<<dim3((NREL + 3) / 4), blk, 0, stream>>>(relE, Rn, NREL);

    for (int t = 0; t < 3; ++t) {
        const int* ed = edges + (size_t)t * NEDGES * 3;
        // ---- layer 1 ----
        gemm_mfma<0><<<GR, blk, 0, stream>>>(Rn, pWm1, RW, NREL, nullptr, nullptr, nullptr, nullptr);
        gemm_mfma<0><<<GN, blk, 0, stream>>>(A,  pWm1, B,  NNODES, nullptr, nullptr, nullptr, nullptr);
        hipMemsetAsync(C, 0, NM * sizeof(float), stream);
        hipMemsetAsync(deg, 0, NNODES * sizeof(float), stream);
        edge_scatter<<<egrid, blk, 0, stream>>>(ed, B, RW, C, deg, NEDGES, 1);
        gemm_mfma<1><<<GN, blk, 0, stream>>>(A, pWl1, B, NNODES, C, deg, nullptr, nullptr);
        // ---- layer 2 ----
        gemm_mfma<0><<<GR, blk, 0, stream>>>(Rn, pWm2, RW, NREL, nullptr, nullptr, nullptr, nullptr);
        gemm_mfma<0><<<GN, blk, 0, stream>>>(B, pWm2, Dout, NNODES, nullptr, nullptr, nullptr, nullptr);
        hipMemsetAsync(C, 0, NM * sizeof(float), stream);
        edge_scatter<<<egrid, blk, 0, stream>>>(ed, Dout, RW, C, deg, NEDGES, 0);
        // cur = l2norm(agg/deg + B@Wl2)  (fused)
        gemm_mfma<2><<<GN, blk, 0, stream>>>(B, pWl2, Dout, NNODES, C, deg, nullptr, nullptr);
        // h' = l2norm(sigmoid(A@Wtg + bias)*cur + (1-g)*h)  (fused; in-place safe)
        float* outp = (t == 2) ? Dout : A;
        gemm_mfma<3><<<GN, blk, 0, stream>>>(A, pWtg, outp, NNODES, nullptr, nullptr, bias, Dout);
    }
}

// Round 3
// 2089.036 us; speedup vs baseline: 1.8586x; 1.2088x over previous
//
#include <hip/hip_runtime.h>
#include <math.h>

#define DIMN   200
#define NNODES 100000
#define NREL   500
#define NEDGES 200000
#define KSTEPS 7            // K padded 200 -> 224 = 7*32
#define NB16   16           // N padded 200 -> 256
#define WPK_ELEMS (KSTEPS * NB16 * 64 * 8)   // 57344 bf16 per weight
#define LDA    232          // LDS A-tile stride in bf16 (pad: 2-way max bank aliasing)
#define SCAN_B 1024

typedef float  v4f  __attribute__((ext_vector_type(4)));
typedef __bf16 v8bf __attribute__((ext_vector_type(8)));
typedef __bf16 v4bf __attribute__((ext_vector_type(4)));

// ---------------- l2norm: one wave per row ----------------
__launch_bounds__(256)
__global__ void l2norm_rows(const float* __restrict__ in, float* __restrict__ out, int nrows)
{
    int wave = (int)((blockIdx.x * blockDim.x + threadIdx.x) >> 6);
    int lane = threadIdx.x & 63;
    if (wave >= nrows) return;
    const float* row = in + (size_t)wave * DIMN;
    float v0 = row[lane];
    float v1 = row[lane + 64];
    float v2 = row[lane + 128];
    float v3 = (lane < 8) ? row[lane + 192] : 0.0f;
    float ss = v0*v0 + v1*v1 + v2*v2 + v3*v3;
    #pragma unroll
    for (int off = 32; off; off >>= 1) ss += __shfl_xor(ss, off, 64);
    float s = 1.0f / fmaxf(sqrtf(ss), 1e-12f);
    float* orow = out + (size_t)wave * DIMN;
    orow[lane]       = v0 * s;
    orow[lane + 64]  = v1 * s;
    orow[lane + 128] = v2 * s;
    if (lane < 8) orow[lane + 192] = v3 * s;
}

// ---------------- CSR build ----------------
__launch_bounds__(256)
__global__ void edge_hist(const int* __restrict__ edges, int* __restrict__ counts, int nedges)
{
    int e = blockIdx.x * 256 + threadIdx.x;
    if (e < nedges) atomicAdd(&counts[edges[e * 3 + 2]], 1);
}

__launch_bounds__(SCAN_B)
__global__ void scan1(const int* __restrict__ counts, int* __restrict__ tmp,
                      int* __restrict__ bsum, int n)
{
    __shared__ int sh[SCAN_B];
    int i = blockIdx.x * SCAN_B + threadIdx.x;
    int v = (i < n) ? counts[i] : 0;
    sh[threadIdx.x] = v;
    __syncthreads();
    for (int off = 1; off < SCAN_B; off <<= 1) {
        int t = (threadIdx.x >= off) ? sh[threadIdx.x - off] : 0;
        __syncthreads();
        sh[threadIdx.x] += t;
        __syncthreads();
    }
    if (i < n) tmp[i] = sh[threadIdx.x];                    // inclusive
    if (threadIdx.x == SCAN_B - 1) bsum[blockIdx.x] = sh[threadIdx.x];
}

__launch_bounds__(128)
__global__ void scan2(int* __restrict__ bsum, int nb)        // exclusive, single block
{
    __shared__ int sh[128];
    int v = (threadIdx.x < nb) ? bsum[threadIdx.x] : 0;
    sh[threadIdx.x] = v;
    __syncthreads();
    for (int off = 1; off < 128; off <<= 1) {
        int t = (threadIdx.x >= off) ? sh[threadIdx.x - off] : 0;
        __syncthreads();
        sh[threadIdx.x] += t;
        __syncthreads();
    }
    if (threadIdx.x < nb) bsum[threadIdx.x] = sh[threadIdx.x] - v;
}

__launch_bounds__(SCAN_B)
__global__ void scan3(const int* __restrict__ tmp, const int* __restrict__ bsum,
                      int* __restrict__ offs, int n)
{
    int i = blockIdx.x * SCAN_B + threadIdx.x;
    if (i < n) offs[i + 1] = tmp[i] + bsum[blockIdx.x];
    if (i == 0) offs[0] = 0;
}

__launch_bounds__(256)
__global__ void edge_fill(const int* __restrict__ edges, const int* __restrict__ offs,
                          int* __restrict__ cursor, int2* __restrict__ sorted, int nedges)
{
    int e = blockIdx.x * 256 + threadIdx.x;
    if (e >= nedges) return;
    int s = edges[e * 3 + 0];
    int r = edges[e * 3 + 1];
    int d = edges[e * 3 + 2];
    int p = offs[d] + atomicAdd(&cursor[d], 1);
    sorted[p] = make_int2(s, r);
}

// ---------------- gather-aggregate: one wave per node, no atomics ----------------
__launch_bounds__(256)
__global__ void csr_aggregate(const int* __restrict__ offs, const int2* __restrict__ sorted,
                              const float* __restrict__ HW, const float* __restrict__ RW,
                              float* __restrict__ agg, float* __restrict__ deg, int nnodes)
{
    int wave = (int)((blockIdx.x * blockDim.x + threadIdx.x) >> 6);
    int lane = threadIdx.x & 63;
    if (wave >= nnodes) return;
    int beg = offs[wave], end = offs[wave + 1];
    float a0 = 0.f, a1 = 0.f, a2 = 0.f, a3 = 0.f;
    for (int e = beg; e < end; ++e) {
        int2 sr = sorted[e];
        const float* hs = HW + (size_t)sr.x * DIMN;
        const float* rr = RW + (size_t)sr.y * DIMN;
        a0 += hs[lane]       + rr[lane];
        a1 += hs[lane + 64]  + rr[lane + 64];
        a2 += hs[lane + 128] + rr[lane + 128];
        if (lane < 8) a3 += hs[lane + 192] + rr[lane + 192];
    }
    float* ad = agg + (size_t)wave * DIMN;
    ad[lane]       = a0;
    ad[lane + 64]  = a1;
    ad[lane + 128] = a2;
    if (lane < 8) ad[lane + 192] = a3;
    if (lane == 0) deg[wave] = (float)(end - beg);
}

// ---------------- weight pack: fp32 W[200x200] -> bf16 MFMA-B-fragment-linear ----------------
__launch_bounds__(256)
__global__ void pack_w(const float* __restrict__ W0, const float* __restrict__ W1,
                       const float* __restrict__ W2, const float* __restrict__ W3,
                       const float* __restrict__ W4, __bf16* __restrict__ out)
{
    int id = blockIdx.x * 256 + threadIdx.x;
    const int nchunk = KSTEPS * NB16 * 64;        // 7168
    if (id >= 5 * nchunk) return;
    int wi = id / nchunk;
    int c  = id % nchunk;
    const float* W = wi == 0 ? W0 : wi == 1 ? W1 : wi == 2 ? W2 : wi == 3 ? W3 : W4;
    int s    = c >> 10;
    int nb   = (c & 1023) >> 6;
    int lane = c & 63;
    int kbase = s * 32 + (lane >> 4) * 8;
    int n     = nb * 16 + (lane & 15);
    __bf16* dst = out + (size_t)wi * WPK_ELEMS + (size_t)c * 8;
    #pragma unroll
    for (int j = 0; j < 8; ++j) {
        int k = kbase + j;
        float v = (k < DIMN && n < DIMN) ? W[k * DIMN + n] : 0.0f;
        dst[j] = (__bf16)v;
    }
}

// ---------------- MFMA GEMM with LDS-staged bf16 A-tile ----------------
// Block: 256 thr (4 waves), BM=64, BN=256. Wave w covers cols w*64..w*64+63.
// EPI 0: Out = acc
// EPI 1: Out = acc + Agg/max(Deg,1)
// EPI 2: Out = l2norm_row(acc + Agg/max(Deg,1))
// EPI 3: g = sigmoid(acc + Bias); Out = l2norm_row(g*Cur + (1-g)*In)
template<int EPI>
__launch_bounds__(256)
__global__ void gemm_mfma(const float* __restrict__ In, const __bf16* __restrict__ Wpk,
                          float* __restrict__ Out, int M,
                          const float* __restrict__ Agg, const float* __restrict__ Deg,
                          const float* __restrict__ Bias, const float* __restrict__ Cur)
{
    const int tid  = threadIdx.x;
    const int w    = tid >> 6;
    const int lane = tid & 63;
    const int rlo  = lane & 15;     // A row / D col within 16-tile
    const int g    = lane >> 4;     // k-octet / D row-quad
    const int bm   = blockIdx.x * 64;

    __shared__ __bf16 Asb[64][LDA];
    __shared__ float  rsq[64][4];

    // ---- stage A-tile: fp32 -> bf16, each element converted once ----
    {
        const int srow = tid >> 2;          // 0..63
        const int sc   = tid & 3;           // 0..3
        int gr = bm + srow;
        const float4* rp = (const float4*)(In + (size_t)gr * DIMN);
        bool valid = (gr < M);
        #pragma unroll
        for (int q0 = 0; q0 < 52; q0 += 4) {
            int q = q0 + sc;                 // 0..51, row has 50 float4s
            if (q < 50) {
                float4 f = valid ? rp[q] : make_float4(0.f, 0.f, 0.f, 0.f);
                v4bf b;
                b[0] = (__bf16)f.x; b[1] = (__bf16)f.y; b[2] = (__bf16)f.z; b[3] = (__bf16)f.w;
                *(v4bf*)&Asb[srow][q * 4] = b;
            }
        }
        // zero pad cols 200..231
        v8bf z = {};
        *(v8bf*)&Asb[srow][200 + sc * 8] = z;
    }
    __syncthreads();

    v4f acc[4][4];
    #pragma unroll
    for (int mi = 0; mi < 4; ++mi)
        #pragma unroll
        for (int ni = 0; ni < 4; ++ni)
            acc[mi][ni] = (v4f){0.f, 0.f, 0.f, 0.f};

    const __bf16* wb = Wpk + (size_t)((w * 4) * 64 + lane) * 8;
    v8bf bv[4], bvn[4];
    #pragma unroll
    for (int ni = 0; ni < 4; ++ni)
        bv[ni] = *(const v8bf*)(wb + (size_t)ni * 64 * 8);

    for (int s = 0; s < KSTEPS; ++s) {
        if (s < KSTEPS - 1) {
            const __bf16* wn = wb + (size_t)(s + 1) * NB16 * 64 * 8;
            #pragma unroll
            for (int ni = 0; ni < 4; ++ni)
                bvn[ni] = *(const v8bf*)(wn + (size_t)ni * 64 * 8);
        }
        #pragma unroll
        for (int mi = 0; mi < 4; ++mi) {
            v8bf a = *(const v8bf*)&Asb[mi * 16 + rlo][s * 32 + g * 8];
            #pragma unroll
            for (int ni = 0; ni < 4; ++ni)
                acc[mi][ni] = __builtin_amdgcn_mfma_f32_16x16x32_bf16(a, bv[ni], acc[mi][ni], 0, 0, 0);
        }
        #pragma unroll
        for (int ni = 0; ni < 4; ++ni) bv[ni] = bvn[ni];
    }

    // ---- epilogue ----
    // D layout: row_local = mi*16 + g*4 + reg ; col = w*64 + ni*16 + rlo
    if (EPI == 0 || EPI == 1) {
        #pragma unroll
        for (int mi = 0; mi < 4; ++mi) {
            #pragma unroll
            for (int reg = 0; reg < 4; ++reg) {
                int r = bm + mi * 16 + g * 4 + reg;
                if (r >= M) continue;
                float rdeg = (EPI == 1) ? 1.0f / fmaxf(Deg[r], 1.0f) : 0.0f;
                #pragma unroll
                for (int ni = 0; ni < 4; ++ni) {
                    int c = w * 64 + ni * 16 + rlo;
                    if (c >= DIMN) continue;
                    float v = acc[mi][ni][reg];
                    if (EPI == 1) v += Agg[(size_t)r * DIMN + c] * rdeg;
                    Out[(size_t)r * DIMN + c] = v;
                }
            }
        }
    } else {
        #pragma unroll
        for (int mi = 0; mi < 4; ++mi) {
            #pragma unroll
            for (int reg = 0; reg < 4; ++reg) {
                int r = bm + mi * 16 + g * 4 + reg;
                float rdeg = (EPI == 2 && r < M) ? 1.0f / fmaxf(Deg[r], 1.0f) : 0.0f;
                #pragma unroll
                for (int ni = 0; ni < 4; ++ni) {
                    int c = w * 64 + ni * 16 + rlo;
                    float v = 0.0f;
                    if (r < M && c < DIMN) {
                        if (EPI == 2) {
                            v = acc[mi][ni][reg] + Agg[(size_t)r * DIMN + c] * rdeg;
                        } else { // EPI == 3
                            float gl = acc[mi][ni][reg] + Bias[c];
                            float gg = 1.0f / (1.0f + __expf(-gl));
                            v = gg * Cur[(size_t)r * DIMN + c] + (1.0f - gg) * In[(size_t)r * DIMN + c];
                        }
                    }
                    acc[mi][ni][reg] = v;
                }
            }
        }
        #pragma unroll
        for (int mi = 0; mi < 4; ++mi) {
            #pragma unroll
            for (int reg = 0; reg < 4; ++reg) {
                float ss = 0.0f;
                #pragma unroll
                for (int ni = 0; ni < 4; ++ni) ss += acc[mi][ni][reg] * acc[mi][ni][reg];
                ss += __shfl_xor(ss, 1, 64);
                ss += __shfl_xor(ss, 2, 64);
                ss += __shfl_xor(ss, 4, 64);
                ss += __shfl_xor(ss, 8, 64);
                if (rlo == 0) rsq[mi * 16 + g * 4 + reg][w] = ss;
            }
        }
        __syncthreads();
        #pragma unroll
        for (int mi = 0; mi < 4; ++mi) {
            #pragma unroll
            for (int reg = 0; reg < 4; ++reg) {
                int rl = mi * 16 + g * 4 + reg;
                int r  = bm + rl;
                float tot = rsq[rl][0] + rsq[rl][1] + rsq[rl][2] + rsq[rl][3];
                float sc  = 1.0f / fmaxf(sqrtf(tot), 1e-12f);
                if (r >= M) continue;
                #pragma unroll
                for (int ni = 0; ni < 4; ++ni) {
                    int c = w * 64 + ni * 16 + rlo;
                    if (c >= DIMN) continue;
                    Out[(size_t)r * DIMN + c] = acc[mi][ni][reg] * sc;
                }
            }
        }
    }
}

extern "C" void kernel_launch(void* const* d_in, const int* in_sizes, int n_in,
                              void* d_out, int out_size, void* d_ws, size_t ws_size,
                              hipStream_t stream)
{
    const int*   edges = (const int*)  d_in[0];
    const float* ent   = (const float*)d_in[1];
    const float* relE  = (const float*)d_in[2];
    const float* Wm1   = (const float*)d_in[3];
    const float* Wl1   = (const float*)d_in[4];
    const float* Wm2   = (const float*)d_in[5];
    const float* Wl2   = (const float*)d_in[6];
    const float* Wtg   = (const float*)d_in[7];
    const float* bias  = (const float*)d_in[8];
    float* Dout = (float*)d_out;

    const size_t NM = (size_t)NNODES * DIMN;
    float* A    = (float*)d_ws;                      // h
    float* B    = A + NM;                            // layer-1 intermediates
    float* C    = B + NM;                            // agg
    float* Rn   = C + NM;                            // normalized relations
    float* RW   = Rn + (size_t)NREL * DIMN;          // r @ W_msg
    float* deg  = RW + (size_t)NREL * DIMN;          // degrees (float); aliased as scan tmp
    __bf16* Wpk = (__bf16*)(deg + NNODES);           // 5 packed weights
    __bf16* pWm1 = Wpk + 0 * (size_t)WPK_ELEMS;
    __bf16* pWl1 = Wpk + 1 * (size_t)WPK_ELEMS;
    __bf16* pWm2 = Wpk + 2 * (size_t)WPK_ELEMS;
    __bf16* pWl2 = Wpk + 3 * (size_t)WPK_ELEMS;
    __bf16* pWtg = Wpk + 4 * (size_t)WPK_ELEMS;
    int*  counts = (int*)(Wpk + 5 * (size_t)WPK_ELEMS);  // also reused as cursor
    int2* sorted = (int2*)(counts + NNODES);
    int*  offs   = (int*)(sorted + NEDGES);
    int*  bsum   = offs + (NNODES + 1);
    int*  stmp   = (int*)deg;                        // scan tmp aliases deg (deg written later)

    dim3 blk(256);
    const int GN = (NNODES + 63) / 64;
    const int GR = (NREL + 63) / 64;
    dim3 ngrid((NNODES + 3) / 4);
    dim3 egrid((NEDGES + 255) / 256);
    const int NSB = (NNODES + SCAN_B - 1) / SCAN_B;  // 98 scan blocks

    pack_w<<<dim3((5 * KSTEPS * NB16 * 64 + 255) / 256), blk, 0, stream>>>(Wm1, Wl1, Wm2, Wl2, Wtg, Wpk);
    l2norm_rows<<<ngrid, blk, 0, stream>>>(ent, A, NNODES);
    l2norm_rows<<<dim3((NREL + 3) / 4), blk, 0, stream>>>(relE, Rn, NREL);

    for (int t = 0; t < 3; ++t) {
        const int* ed = edges + (size_t)t * NEDGES * 3;
        // ---- CSR build for this timestep ----
        hipMemsetAsync(counts, 0, NNODES * sizeof(int), stream);
        edge_hist<<<egrid, blk, 0, stream>>>(ed, counts, NEDGES);
        scan1<<<NSB, SCAN_B, 0, stream>>>(counts, stmp, bsum, NNODES);
        scan2<<<1, 128, 0, stream>>>(bsum, NSB);
        scan3<<<NSB, SCAN_B, 0, stream>>>(stmp, bsum, offs, NNODES);
        hipMemsetAsync(counts, 0, NNODES * sizeof(int), stream);   // now cursor
        edge_fill<<<egrid, blk, 0, stream>>>(ed, offs, counts, sorted, NEDGES);
        // ---- layer 1 ----
        gemm_mfma<0><<<GR, blk, 0, stream>>>(Rn, pWm1, RW, NREL, nullptr, nullptr, nullptr, nullptr);
        gemm_mfma<0><<<GN, blk, 0, stream>>>(A,  pWm1, B,  NNODES, nullptr, nullptr, nullptr, nullptr);
        csr_aggregate<<<ngrid, blk, 0, stream>>>(offs, sorted, B, RW, C, deg, NNODES);
        gemm_mfma<1><<<GN, blk, 0, stream>>>(A, pWl1, B, NNODES, C, deg, nullptr, nullptr);
        // ---- layer 2 ----
        gemm_mfma<0><<<GR, blk, 0, stream>>>(Rn, pWm2, RW, NREL, nullptr, nullptr, nullptr, nullptr);
        gemm_mfma<0><<<GN, blk, 0, stream>>>(B, pWm2, Dout, NNODES, nullptr, nullptr, nullptr, nullptr);
        csr_aggregate<<<ngrid, blk, 0, stream>>>(offs, sorted, Dout, RW, C, deg, NNODES);
        gemm_mfma<2><<<GN, blk, 0, stream>>>(B, pWl2, Dout, NNODES, C, deg, nullptr, nullptr);
        // ---- gate + blend + norm (fused) ----
        float* outp = (t == 2) ? Dout : A;
        gemm_mfma<3><<<GN, blk, 0, stream>>>(A, pWtg, outp, NNODES, nullptr, nullptr, bias, Dout);
    }
}

// Round 4
// 1539.767 us; speedup vs baseline: 2.5216x; 1.3567x over previous
//
#include <hip/hip_runtime.h>
#include <math.h>

#define DIMN   200
#define NNODES 100000
#define NREL   500
#define NEDGES 200000
#define KSTEPS 7            // K padded 200 -> 224 = 7*32
#define NB16   16           // N padded 200 -> 256
#define WPK_ELEMS (KSTEPS * NB16 * 64 * 8)   // 57344 bf16 per weight
#define SCAN_B 1024

typedef float  v4f  __attribute__((ext_vector_type(4)));
typedef __bf16 v8bf __attribute__((ext_vector_type(8)));

// ---------------- l2norm: one wave per row; fp32 in, fp32 and/or bf16 out ----------------
__launch_bounds__(256)
__global__ void l2norm_dual(const float* __restrict__ in, float* __restrict__ out32,
                            __bf16* __restrict__ out16, int nrows)
{
    int wave = (int)((blockIdx.x * blockDim.x + threadIdx.x) >> 6);
    int lane = threadIdx.x & 63;
    if (wave >= nrows) return;
    const float* row = in + (size_t)wave * DIMN;
    float v0 = row[lane];
    float v1 = row[lane + 64];
    float v2 = row[lane + 128];
    float v3 = (lane < 8) ? row[lane + 192] : 0.0f;
    float ss = v0*v0 + v1*v1 + v2*v2 + v3*v3;
    #pragma unroll
    for (int off = 32; off; off >>= 1) ss += __shfl_xor(ss, off, 64);
    float s = 1.0f / fmaxf(sqrtf(ss), 1e-12f);
    v0 *= s; v1 *= s; v2 *= s; v3 *= s;
    size_t base = (size_t)wave * DIMN;
    if (out32) {
        out32[base + lane]       = v0;
        out32[base + lane + 64]  = v1;
        out32[base + lane + 128] = v2;
        if (lane < 8) out32[base + lane + 192] = v3;
    }
    out16[base + lane]       = (__bf16)v0;
    out16[base + lane + 64]  = (__bf16)v1;
    out16[base + lane + 128] = (__bf16)v2;
    if (lane < 8) out16[base + lane + 192] = (__bf16)v3;
}

// ---------------- CSR build ----------------
__launch_bounds__(256)
__global__ void edge_hist(const int* __restrict__ edges, int* __restrict__ counts, int nedges)
{
    int e = blockIdx.x * 256 + threadIdx.x;
    if (e < nedges) atomicAdd(&counts[edges[e * 3 + 2]], 1);
}

__launch_bounds__(SCAN_B)
__global__ void scan1(const int* __restrict__ counts, int* __restrict__ tmp,
                      int* __restrict__ bsum, int n)
{
    __shared__ int sh[SCAN_B];
    int i = blockIdx.x * SCAN_B + threadIdx.x;
    int v = (i < n) ? counts[i] : 0;
    sh[threadIdx.x] = v;
    __syncthreads();
    for (int off = 1; off < SCAN_B; off <<= 1) {
        int t = (threadIdx.x >= off) ? sh[threadIdx.x - off] : 0;
        __syncthreads();
        sh[threadIdx.x] += t;
        __syncthreads();
    }
    if (i < n) tmp[i] = sh[threadIdx.x];                    // inclusive
    if (threadIdx.x == SCAN_B - 1) bsum[blockIdx.x] = sh[threadIdx.x];
}

__launch_bounds__(128)
__global__ void scan2(int* __restrict__ bsum, int nb)        // exclusive, single block
{
    __shared__ int sh[128];
    int v = (threadIdx.x < nb) ? bsum[threadIdx.x] : 0;
    sh[threadIdx.x] = v;
    __syncthreads();
    for (int off = 1; off < 128; off <<= 1) {
        int t = (threadIdx.x >= off) ? sh[threadIdx.x - off] : 0;
        __syncthreads();
        sh[threadIdx.x] += t;
        __syncthreads();
    }
    if (threadIdx.x < nb) bsum[threadIdx.x] = sh[threadIdx.x] - v;
}

__launch_bounds__(SCAN_B)
__global__ void scan3(const int* __restrict__ tmp, const int* __restrict__ bsum,
                      int* __restrict__ offs, int n)
{
    int i = blockIdx.x * SCAN_B + threadIdx.x;
    if (i < n) offs[i + 1] = tmp[i] + bsum[blockIdx.x];
    if (i == 0) offs[0] = 0;
}

__launch_bounds__(256)
__global__ void edge_fill(const int* __restrict__ edges, const int* __restrict__ offs,
                          int* __restrict__ cursor, int2* __restrict__ sorted, int nedges)
{
    int e = blockIdx.x * 256 + threadIdx.x;
    if (e >= nedges) return;
    int s = edges[e * 3 + 0];
    int r = edges[e * 3 + 1];
    int d = edges[e * 3 + 2];
    int p = offs[d] + atomicAdd(&cursor[d], 1);
    sorted[p] = make_int2(s, r);
}

// ---------------- weight pack: fp32 W[200x200] -> bf16 MFMA-B-fragment-linear ----------------
__launch_bounds__(256)
__global__ void pack_w(const float* __restrict__ W0, const float* __restrict__ W1,
                       const float* __restrict__ W2, const float* __restrict__ W3,
                       const float* __restrict__ W4, __bf16* __restrict__ out)
{
    int id = blockIdx.x * 256 + threadIdx.x;
    const int nchunk = KSTEPS * NB16 * 64;        // 7168
    if (id >= 5 * nchunk) return;
    int wi = id / nchunk;
    int c  = id % nchunk;
    const float* W = wi == 0 ? W0 : wi == 1 ? W1 : wi == 2 ? W2 : wi == 3 ? W3 : W4;
    int s    = c >> 10;
    int nb   = (c & 1023) >> 6;
    int lane = c & 63;
    int kbase = s * 32 + (lane >> 4) * 8;
    int n     = nb * 16 + (lane & 15);
    __bf16* dst = out + (size_t)wi * WPK_ELEMS + (size_t)c * 8;
    #pragma unroll
    for (int j = 0; j < 8; ++j) {
        int k = kbase + j;
        float v = (k < DIMN && n < DIMN) ? W[k * DIMN + n] : 0.0f;
        dst[j] = (__bf16)v;
    }
}

// ---------------- MFMA GEMM: Out[M x 200](bf16) = In[M x 200](bf16) @ W ----------------
// Block: 256 thr (4 waves), BM=64, BN=256. Direct v8bf global A loads: no LDS, no barrier.
// EPI 0: Out = acc ; EPI 1: Out = sigmoid(acc + Bias)
template<int EPI>
__launch_bounds__(256)
__global__ void gemm_bf(const __bf16* __restrict__ In, const __bf16* __restrict__ Wpk,
                        __bf16* __restrict__ Out, int M, const float* __restrict__ Bias)
{
    const int tid  = threadIdx.x;
    const int w    = tid >> 6;
    const int lane = tid & 63;
    const int rlo  = lane & 15;
    const int g    = lane >> 4;
    const int bm   = blockIdx.x * 64;

    v4f acc[4][4];
    #pragma unroll
    for (int mi = 0; mi < 4; ++mi)
        #pragma unroll
        for (int ni = 0; ni < 4; ++ni)
            acc[mi][ni] = (v4f){0.f, 0.f, 0.f, 0.f};

    const __bf16* wb = Wpk + (size_t)(w * 4 * 64 + lane) * 8;

    for (int s = 0; s < KSTEPS; ++s) {
        v8bf bv[4] = {};
        #pragma unroll
        for (int ni = 0; ni < 4; ++ni)
            if ((w * 4 + ni) * 16 < DIMN)
                bv[ni] = *(const v8bf*)(wb + ((size_t)s * NB16 * 64 + ni * 64) * 8);
        int k0 = s * 32 + g * 8;
        #pragma unroll
        for (int mi = 0; mi < 4; ++mi) {
            int row = bm + mi * 16 + rlo;
            v8bf a = {};
            if (row < M && k0 < DIMN)
                a = *(const v8bf*)(In + (size_t)row * DIMN + k0);
            #pragma unroll
            for (int ni = 0; ni < 4; ++ni)
                if ((w * 4 + ni) * 16 < DIMN)
                    acc[mi][ni] = __builtin_amdgcn_mfma_f32_16x16x32_bf16(a, bv[ni], acc[mi][ni], 0, 0, 0);
        }
    }

    // D layout: row_local = mi*16 + g*4 + reg ; col = w*64 + ni*16 + rlo
    #pragma unroll
    for (int mi = 0; mi < 4; ++mi) {
        #pragma unroll
        for (int reg = 0; reg < 4; ++reg) {
            int r = bm + mi * 16 + g * 4 + reg;
            if (r >= M) continue;
            #pragma unroll
            for (int ni = 0; ni < 4; ++ni) {
                int c = w * 64 + ni * 16 + rlo;
                if (c >= DIMN) continue;
                float v = acc[mi][ni][reg];
                if (EPI == 1) { v += Bias[c]; v = 1.0f / (1.0f + __expf(-v)); }
                Out[(size_t)r * DIMN + c] = (__bf16)v;
            }
        }
    }
}

// ---------------- aggregate + combine: one wave per node, fully coalesced ----------------
// Out[n] = (sum_e HW[src]+RW[rel]) / max(deg,1) + Self[n] ; NORM: l2norm the row.
// Lanes 0..24 own the 25 v8bf chunks of HW rows; lanes 32..56 own RW chunks; shfl_xor(32) merges.
template<int NORM>
__launch_bounds__(256)
__global__ void agg_combine(const int* __restrict__ offs, const int2* __restrict__ sorted,
                            const __bf16* __restrict__ HW, const __bf16* __restrict__ RW,
                            const __bf16* __restrict__ Self, __bf16* __restrict__ Out, int nnodes)
{
    int wave = (int)((blockIdx.x * blockDim.x + threadIdx.x) >> 6);
    int lane = threadIdx.x & 63;
    if (wave >= nnodes) return;
    int beg = offs[wave], end = offs[wave + 1];
    int ch = lane & 31;
    bool act = ch < 25;

    float accf[8] = {};
    for (int e = beg; e < end; ++e) {
        int2 sr = sorted[e];
        const __bf16* base = (lane < 32) ? (HW + (size_t)sr.x * DIMN)
                                         : (RW + (size_t)sr.y * DIMN);
        v8bf v = {};
        if (act) v = *(const v8bf*)(base + ch * 8);
        #pragma unroll
        for (int k = 0; k < 8; ++k) accf[k] += (float)v[k];
    }
    // merge HW-half (lanes 0..24) with RW-half (lanes 32..56)
    #pragma unroll
    for (int k = 0; k < 8; ++k) accf[k] += __shfl_xor(accf[k], 32, 64);

    float rdeg = 1.0f / fmaxf((float)(end - beg), 1.0f);
    float tot[8];
    v8bf sw = {};
    if (act && lane < 32) sw = *(const v8bf*)(Self + (size_t)wave * DIMN + ch * 8);
    #pragma unroll
    for (int k = 0; k < 8; ++k) tot[k] = accf[k] * rdeg + (float)sw[k];

    float scale = 1.0f;
    if (NORM) {
        float ss = 0.0f;
        if (act && lane < 32)
            #pragma unroll
            for (int k = 0; k < 8; ++k) ss += tot[k] * tot[k];
        else ss = 0.0f;
        #pragma unroll
        for (int off = 16; off; off >>= 1) ss += __shfl_xor(ss, off, 64);  // within 32-group
        scale = 1.0f / fmaxf(sqrtf(ss), 1e-12f);
    }
    if (act && lane < 32) {
        v8bf o;
        #pragma unroll
        for (int k = 0; k < 8; ++k) o[k] = (__bf16)(tot[k] * scale);
        *(v8bf*)(Out + (size_t)wave * DIMN + ch * 8) = o;
    }
}

// ---------------- gate blend + l2norm: h' = l2norm(g*cur + (1-g)*h) ----------------
__launch_bounds__(256)
__global__ void gate_blend(const __bf16* __restrict__ Gate, const __bf16* __restrict__ Cur,
                           const float* __restrict__ H32, float* __restrict__ Out32,
                           __bf16* __restrict__ Out16, int nnodes)
{
    int wave = (int)((blockIdx.x * blockDim.x + threadIdx.x) >> 6);
    int lane = threadIdx.x & 63;
    if (wave >= nnodes) return;
    size_t base = (size_t)wave * DIMN;
    float v[4];
    #pragma unroll
    for (int it = 0; it < 4; ++it) {
        int j = lane + 64 * it;
        if (j < DIMN) {
            float gg = (float)Gate[base + j];
            float cc = (float)Cur[base + j];
            float hh = H32[base + j];
            v[it] = gg * cc + (1.0f - gg) * hh;
        } else v[it] = 0.0f;
    }
    float ss = v[0]*v[0] + v[1]*v[1] + v[2]*v[2] + v[3]*v[3];
    #pragma unroll
    for (int off = 32; off; off >>= 1) ss += __shfl_xor(ss, off, 64);
    float s = 1.0f / fmaxf(sqrtf(ss), 1e-12f);
    #pragma unroll
    for (int it = 0; it < 4; ++it) {
        int j = lane + 64 * it;
        if (j < DIMN) {
            float o = v[it] * s;
            Out32[base + j] = o;
            if (Out16) Out16[base + j] = (__bf16)o;
        }
    }
}

extern "C" void kernel_launch(void* const* d_in, const int* in_sizes, int n_in,
                              void* d_out, int out_size, void* d_ws, size_t ws_size,
                              hipStream_t stream)
{
    const int*   edges = (const int*)  d_in[0];
    const float* ent   = (const float*)d_in[1];
    const float* relE  = (const float*)d_in[2];
    const float* Wm1   = (const float*)d_in[3];
    const float* Wl1   = (const float*)d_in[4];
    const float* Wm2   = (const float*)d_in[5];
    const float* Wl2   = (const float*)d_in[6];
    const float* Wtg   = (const float*)d_in[7];
    const float* bias  = (const float*)d_in[8];
    float* Dout = (float*)d_out;

    const size_t NM = (size_t)NNODES * DIMN;
    float*  A32  = (float*)d_ws;                       // h master fp32       (80 MB)
    __bf16* A16  = (__bf16*)(A32 + NM);                // h bf16 mirror       (40 MB)
    __bf16* HW   = A16 + NM;                           // msg GEMM out / gate (40 MB)
    __bf16* Self = HW + NM;                            // self-loop GEMM out  (40 MB)
    __bf16* Bb   = Self + NM;                          // layer-1 out / cur   (40 MB)
    __bf16* Rn16 = Bb + NM;                            // normalized relations
    __bf16* RW16 = Rn16 + (size_t)NREL * DIMN;         // r @ W_msg
    __bf16* Wpk  = RW16 + (size_t)NREL * DIMN;         // 5 packed weights
    __bf16* pWm1 = Wpk + 0 * (size_t)WPK_ELEMS;
    __bf16* pWl1 = Wpk + 1 * (size_t)WPK_ELEMS;
    __bf16* pWm2 = Wpk + 2 * (size_t)WPK_ELEMS;
    __bf16* pWl2 = Wpk + 3 * (size_t)WPK_ELEMS;
    __bf16* pWtg = Wpk + 4 * (size_t)WPK_ELEMS;
    int*  counts = (int*)(Wpk + 5 * (size_t)WPK_ELEMS);
    int2* sorted = (int2*)(counts + NNODES);
    int*  offs   = (int*)(sorted + NEDGES);
    int*  bsum   = offs + (NNODES + 1);
    int*  stmp   = bsum + 256;

    dim3 blk(256);
    const int GN = (NNODES + 63) / 64;      // 1563
    const int GR = (NREL + 63) / 64;        // 8
    dim3 ngrid((NNODES + 3) / 4);
    dim3 egrid((NEDGES + 255) / 256);
    const int NSB = (NNODES + SCAN_B - 1) / SCAN_B;

    pack_w<<<dim3((5 * KSTEPS * NB16 * 64 + 255) / 256), blk, 0, stream>>>(Wm1, Wl1, Wm2, Wl2, Wtg, Wpk);
    l2norm_dual<<<ngrid, blk, 0, stream>>>(ent, A32, A16, NNODES);
    l2norm_dual<<<dim3((NREL + 3) / 4), blk, 0, stream>>>(relE, nullptr, Rn16, NREL);

    for (int t = 0; t < 3; ++t) {
        const int* ed = edges + (size_t)t * NEDGES * 3;
        // ---- CSR build ----
        hipMemsetAsync(counts, 0, NNODES * sizeof(int), stream);
        edge_hist<<<egrid, blk, 0, stream>>>(ed, counts, NEDGES);
        scan1<<<NSB, SCAN_B, 0, stream>>>(counts, stmp, bsum, NNODES);
        scan2<<<1, 128, 0, stream>>>(bsum, NSB);
        scan3<<<NSB, SCAN_B, 0, stream>>>(stmp, bsum, offs, NNODES);
        hipMemsetAsync(counts, 0, NNODES * sizeof(int), stream);   // cursor
        edge_fill<<<egrid, blk, 0, stream>>>(ed, offs, counts, sorted, NEDGES);
        // ---- layer 1 ----
        gemm_bf<0><<<GR, blk, 0, stream>>>(Rn16, pWm1, RW16, NREL, nullptr);
        gemm_bf<0><<<GN, blk, 0, stream>>>(A16,  pWm1, HW,   NNODES, nullptr);
        gemm_bf<0><<<GN, blk, 0, stream>>>(A16,  pWl1, Self, NNODES, nullptr);
        agg_combine<0><<<ngrid, blk, 0, stream>>>(offs, sorted, HW, RW16, Self, Bb, NNODES);
        // ---- layer 2 ----
        gemm_bf<0><<<GR, blk, 0, stream>>>(Rn16, pWm2, RW16, NREL, nullptr);
        gemm_bf<0><<<GN, blk, 0, stream>>>(Bb,   pWm2, HW,   NNODES, nullptr);
        gemm_bf<0><<<GN, blk, 0, stream>>>(Bb,   pWl2, Self, NNODES, nullptr);
        agg_combine<1><<<ngrid, blk, 0, stream>>>(offs, sorted, HW, RW16, Self, Bb, NNODES);  // cur -> Bb
        // ---- gate (sigmoid fused) -> HW ----
        gemm_bf<1><<<GN, blk, 0, stream>>>(A16, pWtg, HW, NNODES, bias);
        // ---- h' = l2norm(gate*cur + (1-gate)*h) ----
        if (t == 2)
            gate_blend<<<ngrid, blk, 0, stream>>>(HW, Bb, A32, Dout, nullptr, NNODES);
        else
            gate_blend<<<ngrid, blk, 0, stream>>>(HW, Bb, A32, A32, A16, NNODES);
    }
}

// Round 5
// 1450.254 us; speedup vs baseline: 2.6773x; 1.0617x over previous
//
#include <hip/hip_runtime.h>
#include <math.h>

#define DIMN   200
#define NNODES 100000
#define NREL   500
#define NEDGES 200000
#define KSTEPS 7            // K padded 200 -> 224 = 7*32
#define NB16   16           // N padded 200 -> 256
#define WPK_ELEMS (KSTEPS * NB16 * 64 * 8)   // 57344 bf16 per weight
#define SCAN_B 1024
#define NBN    6252         // node fragment-blocks allocated (grid 1563*4 covers 6252)
#define NBR    32           // relation fragment-blocks (512 rows)
#define FRAG_STRIDE 3584    // elems per 16-row fragment block = KSTEPS*512

typedef float  v4f  __attribute__((ext_vector_type(4)));
typedef __bf16 v8bf __attribute__((ext_vector_type(8)));

// fragment-linear layout for GEMM A-inputs:
// chunk c = s*4+g (c in 0..27, k = c*8..c*8+7), row r in 0..15 of node-block nb
__device__ __forceinline__ size_t frag_chunk(int nb, int c, int r) {
    return (size_t)(nb * KSTEPS + (c >> 2)) * 512 + (size_t)((c & 3) * 128 + r * 8);
}

// ---------------- l2norm: 2 nodes per wave (32 lanes each); row-major fp32 in ----------------
// outputs: optional fp32 row-major + bf16 fragment-layout
__launch_bounds__(256)
__global__ void l2norm_frag(const float* __restrict__ in, float* __restrict__ out32,
                            __bf16* __restrict__ outf, int nrows)
{
    int idx  = blockIdx.x * 256 + threadIdx.x;
    int node = idx >> 5;
    int ch   = idx & 31;
    if (node >= nrows) return;
    float v[8] = {};
    if (ch < 25) {
        const float4* p = (const float4*)(in + (size_t)node * DIMN + ch * 8);
        float4 f0 = p[0], f1 = p[1];
        v[0]=f0.x; v[1]=f0.y; v[2]=f0.z; v[3]=f0.w;
        v[4]=f1.x; v[5]=f1.y; v[6]=f1.z; v[7]=f1.w;
    }
    float ss = 0.0f;
    #pragma unroll
    for (int k = 0; k < 8; ++k) ss += v[k] * v[k];
    #pragma unroll
    for (int off = 16; off; off >>= 1) ss += __shfl_xor(ss, off, 64);   // within 32-group
    float s = 1.0f / fmaxf(sqrtf(ss), 1e-12f);
    #pragma unroll
    for (int k = 0; k < 8; ++k) v[k] *= s;
    if (out32 && ch < 25) {
        float4* q = (float4*)(out32 + (size_t)node * DIMN + ch * 8);
        q[0] = make_float4(v[0], v[1], v[2], v[3]);
        q[1] = make_float4(v[4], v[5], v[6], v[7]);
    }
    if (ch < 28) {          // chunks 25..27 write zero k-padding
        v8bf o;
        #pragma unroll
        for (int k = 0; k < 8; ++k) o[k] = (__bf16)v[k];
        *(v8bf*)(outf + frag_chunk(node >> 4, ch, node & 15)) = o;
    }
}

// ---------------- CSR build ----------------
__launch_bounds__(256)
__global__ void edge_hist(const int* __restrict__ edges, int* __restrict__ counts, int nedges)
{
    int e = blockIdx.x * 256 + threadIdx.x;
    if (e < nedges) atomicAdd(&counts[edges[e * 3 + 2]], 1);
}

__launch_bounds__(SCAN_B)
__global__ void scan1(const int* __restrict__ counts, int* __restrict__ tmp,
                      int* __restrict__ bsum, int n)
{
    __shared__ int sh[SCAN_B];
    int i = blockIdx.x * SCAN_B + threadIdx.x;
    int v = (i < n) ? counts[i] : 0;
    sh[threadIdx.x] = v;
    __syncthreads();
    for (int off = 1; off < SCAN_B; off <<= 1) {
        int t = (threadIdx.x >= off) ? sh[threadIdx.x - off] : 0;
        __syncthreads();
        sh[threadIdx.x] += t;
        __syncthreads();
    }
    if (i < n) tmp[i] = sh[threadIdx.x];
    if (threadIdx.x == SCAN_B - 1) bsum[blockIdx.x] = sh[threadIdx.x];
}

__launch_bounds__(128)
__global__ void scan2(int* __restrict__ bsum, int nb)
{
    __shared__ int sh[128];
    int v = (threadIdx.x < nb) ? bsum[threadIdx.x] : 0;
    sh[threadIdx.x] = v;
    __syncthreads();
    for (int off = 1; off < 128; off <<= 1) {
        int t = (threadIdx.x >= off) ? sh[threadIdx.x - off] : 0;
        __syncthreads();
        sh[threadIdx.x] += t;
        __syncthreads();
    }
    if (threadIdx.x < nb) bsum[threadIdx.x] = sh[threadIdx.x] - v;
}

__launch_bounds__(SCAN_B)
__global__ void scan3(const int* __restrict__ tmp, const int* __restrict__ bsum,
                      int* __restrict__ offs, int n)
{
    int i = blockIdx.x * SCAN_B + threadIdx.x;
    if (i < n) offs[i + 1] = tmp[i] + bsum[blockIdx.x];
    if (i == 0) offs[0] = 0;
}

__launch_bounds__(256)
__global__ void edge_fill(const int* __restrict__ edges, const int* __restrict__ offs,
                          int* __restrict__ cursor, int2* __restrict__ sorted, int nedges)
{
    int e = blockIdx.x * 256 + threadIdx.x;
    if (e >= nedges) return;
    int s = edges[e * 3 + 0];
    int r = edges[e * 3 + 1];
    int d = edges[e * 3 + 2];
    int p = offs[d] + atomicAdd(&cursor[d], 1);
    sorted[p] = make_int2(s, r);
}

// ---------------- weight pack: fp32 W[200x200] -> bf16 MFMA-B-fragment-linear ----------------
__launch_bounds__(256)
__global__ void pack_w(const float* __restrict__ W0, const float* __restrict__ W1,
                       const float* __restrict__ W2, const float* __restrict__ W3,
                       const float* __restrict__ W4, __bf16* __restrict__ out)
{
    int id = blockIdx.x * 256 + threadIdx.x;
    const int nchunk = KSTEPS * NB16 * 64;        // 7168
    if (id >= 5 * nchunk) return;
    int wi = id / nchunk;
    int c  = id % nchunk;
    const float* W = wi == 0 ? W0 : wi == 1 ? W1 : wi == 2 ? W2 : wi == 3 ? W3 : W4;
    int s    = c >> 10;
    int nb   = (c & 1023) >> 6;
    int lane = c & 63;
    int kbase = s * 32 + (lane >> 4) * 8;
    int n     = nb * 16 + (lane & 15);
    __bf16* dst = out + (size_t)wi * WPK_ELEMS + (size_t)c * 8;
    #pragma unroll
    for (int j = 0; j < 8; ++j) {
        int k = kbase + j;
        float v = (k < DIMN && n < DIMN) ? W[k * DIMN + n] : 0.0f;
        dst[j] = (__bf16)v;
    }
}

// ---------------- MFMA GEMM: Out[M x 200](bf16 row-major) = Inf(frag) @ W ----------------
// Block: 256 thr (4 waves), BM=64, BN=256. A-loads: 1 KB fully-coalesced per instruction.
// EPI 0: Out = acc ; EPI 1: Out = sigmoid(acc + Bias)
template<int EPI>
__launch_bounds__(256)
__global__ void gemm_bf(const __bf16* __restrict__ Inf, const __bf16* __restrict__ Wpk,
                        __bf16* __restrict__ Out, int M, const float* __restrict__ Bias)
{
    const int tid  = threadIdx.x;
    const int w    = tid >> 6;
    const int lane = tid & 63;
    const int rlo  = lane & 15;
    const int g    = lane >> 4;
    const int nb0  = blockIdx.x * 4;
    const int bm   = blockIdx.x * 64;

    v4f acc[4][4];
    #pragma unroll
    for (int mi = 0; mi < 4; ++mi)
        #pragma unroll
        for (int ni = 0; ni < 4; ++ni)
            acc[mi][ni] = (v4f){0.f, 0.f, 0.f, 0.f};

    const __bf16* wb = Wpk + (size_t)(w * 4 * 64 + lane) * 8;

    for (int s = 0; s < KSTEPS; ++s) {
        v8bf bv[4] = {};
        #pragma unroll
        for (int ni = 0; ni < 4; ++ni)
            if ((w * 4 + ni) * 16 < DIMN)
                bv[ni] = *(const v8bf*)(wb + ((size_t)s * NB16 * 64 + ni * 64) * 8);
        #pragma unroll
        for (int mi = 0; mi < 4; ++mi) {
            // fully coalesced: lane i reads [base + i*16B]
            v8bf a = *(const v8bf*)(Inf + (size_t)((nb0 + mi) * KSTEPS + s) * 512 + lane * 8);
            #pragma unroll
            for (int ni = 0; ni < 4; ++ni)
                if ((w * 4 + ni) * 16 < DIMN)
                    acc[mi][ni] = __builtin_amdgcn_mfma_f32_16x16x32_bf16(a, bv[ni], acc[mi][ni], 0, 0, 0);
        }
    }

    // D layout: row_local = mi*16 + g*4 + reg ; col = w*64 + ni*16 + rlo
    #pragma unroll
    for (int mi = 0; mi < 4; ++mi) {
        #pragma unroll
        for (int reg = 0; reg < 4; ++reg) {
            int r = bm + mi * 16 + g * 4 + reg;
            if (r >= M) continue;
            #pragma unroll
            for (int ni = 0; ni < 4; ++ni) {
                int c = w * 64 + ni * 16 + rlo;
                if (c >= DIMN) continue;
                float v = acc[mi][ni][reg];
                if (EPI == 1) { v += Bias[c]; v = 1.0f / (1.0f + __expf(-v)); }
                Out[(size_t)r * DIMN + c] = (__bf16)v;
            }
        }
    }
}

// ---------------- aggregate + combine: one wave per node ----------------
// Outf[n](frag) = (sum_e HW[src]+RW[rel]) / max(deg,1) + Self[n] ; NORM: l2norm the row.
template<int NORM>
__launch_bounds__(256)
__global__ void agg_combine(const int* __restrict__ offs, const int2* __restrict__ sorted,
                            const __bf16* __restrict__ HW, const __bf16* __restrict__ RW,
                            const __bf16* __restrict__ Self, __bf16* __restrict__ Outf, int nnodes)
{
    int wave = (int)((blockIdx.x * blockDim.x + threadIdx.x) >> 6);
    int lane = threadIdx.x & 63;
    if (wave >= nnodes) return;
    int beg = offs[wave], end = offs[wave + 1];
    int ch = lane & 31;
    bool act = ch < 25;

    float accf[8] = {};
    for (int e = beg; e < end; ++e) {
        int2 sr = sorted[e];
        const __bf16* base = (lane < 32) ? (HW + (size_t)sr.x * DIMN)
                                         : (RW + (size_t)sr.y * DIMN);
        v8bf v = {};
        if (act) v = *(const v8bf*)(base + ch * 8);
        #pragma unroll
        for (int k = 0; k < 8; ++k) accf[k] += (float)v[k];
    }
    #pragma unroll
    for (int k = 0; k < 8; ++k) accf[k] += __shfl_xor(accf[k], 32, 64);

    float rdeg = 1.0f / fmaxf((float)(end - beg), 1.0f);
    float tot[8];
    v8bf sw = {};
    if (act && lane < 32) sw = *(const v8bf*)(Self + (size_t)wave * DIMN + ch * 8);
    #pragma unroll
    for (int k = 0; k < 8; ++k) tot[k] = accf[k] * rdeg + (float)sw[k];

    float scale = 1.0f;
    if (NORM) {
        float ss = 0.0f;
        if (act && lane < 32)
            #pragma unroll
            for (int k = 0; k < 8; ++k) ss += tot[k] * tot[k];
        #pragma unroll
        for (int off = 16; off; off >>= 1) ss += __shfl_xor(ss, off, 64);
        scale = 1.0f / fmaxf(sqrtf(ss), 1e-12f);
    }
    if (lane < 32 && ch < 28) {
        v8bf o;
        #pragma unroll
        for (int k = 0; k < 8; ++k) o[k] = (act ? (__bf16)(tot[k] * scale) : (__bf16)0.0f);
        *(v8bf*)(Outf + frag_chunk(wave >> 4, ch, wave & 15)) = o;
    }
}

// ---------------- gate blend + l2norm: 2 nodes/wave ----------------
// h' = l2norm(g*cur + (1-g)*h) ; Gate row-major bf16, Curf fragment bf16, H32 row-major fp32
__launch_bounds__(256)
__global__ void gate_blend(const __bf16* __restrict__ Gate, const __bf16* __restrict__ Curf,
                           const float* __restrict__ H32, float* __restrict__ Out32,
                           __bf16* __restrict__ Outf, int nnodes)
{
    int idx  = blockIdx.x * 256 + threadIdx.x;
    int node = idx >> 5;
    int ch   = idx & 31;
    if (node >= nnodes) return;
    float v[8] = {};
    if (ch < 25) {
        v8bf gg = *(const v8bf*)(Gate + (size_t)node * DIMN + ch * 8);
        v8bf cc = *(const v8bf*)(Curf + frag_chunk(node >> 4, ch, node & 15));
        const float4* hp = (const float4*)(H32 + (size_t)node * DIMN + ch * 8);
        float4 h0 = hp[0], h1 = hp[1];
        float hh[8] = {h0.x, h0.y, h0.z, h0.w, h1.x, h1.y, h1.z, h1.w};
        #pragma unroll
        for (int k = 0; k < 8; ++k) {
            float gf = (float)gg[k];
            v[k] = gf * (float)cc[k] + (1.0f - gf) * hh[k];
        }
    }
    float ss = 0.0f;
    #pragma unroll
    for (int k = 0; k < 8; ++k) ss += v[k] * v[k];
    #pragma unroll
    for (int off = 16; off; off >>= 1) ss += __shfl_xor(ss, off, 64);
    float s = 1.0f / fmaxf(sqrtf(ss), 1e-12f);
    #pragma unroll
    for (int k = 0; k < 8; ++k) v[k] *= s;
    if (ch < 25) {
        float4* q = (float4*)(Out32 + (size_t)node * DIMN + ch * 8);
        q[0] = make_float4(v[0], v[1], v[2], v[3]);
        q[1] = make_float4(v[4], v[5], v[6], v[7]);
    }
    if (Outf && ch < 28) {
        v8bf o;
        #pragma unroll
        for (int k = 0; k < 8; ++k) o[k] = (__bf16)v[k];
        *(v8bf*)(Outf + frag_chunk(node >> 4, ch, node & 15)) = o;
    }
}

extern "C" void kernel_launch(void* const* d_in, const int* in_sizes, int n_in,
                              void* d_out, int out_size, void* d_ws, size_t ws_size,
                              hipStream_t stream)
{
    const int*   edges = (const int*)  d_in[0];
    const float* ent   = (const float*)d_in[1];
    const float* relE  = (const float*)d_in[2];
    const float* Wm1   = (const float*)d_in[3];
    const float* Wl1   = (const float*)d_in[4];
    const float* Wm2   = (const float*)d_in[5];
    const float* Wl2   = (const float*)d_in[6];
    const float* Wtg   = (const float*)d_in[7];
    const float* bias  = (const float*)d_in[8];
    float* Dout = (float*)d_out;

    const size_t NM    = (size_t)NNODES * DIMN;
    const size_t FRAGN = (size_t)NBN * FRAG_STRIDE;     // 22,407,168 elems
    const size_t FRAGR = (size_t)NBR * FRAG_STRIDE;     // 114,688 elems

    float*  A32  = (float*)d_ws;                        // h master fp32 (row-major)
    __bf16* A16f = (__bf16*)(A32 + NM);                 // h bf16 (fragment)
    __bf16* Bbf  = A16f + FRAGN;                        // layer-1 out / cur (fragment)
    __bf16* HW   = Bbf + FRAGN;                         // msg GEMM out / gate (row-major)
    __bf16* Self = HW + NM;                             // self-loop GEMM out (row-major)
    __bf16* RW1  = Self + NM;                           // r @ Wm1 (row-major)
    __bf16* RW2  = RW1 + (size_t)NREL * DIMN;           // r @ Wm2 (row-major)
    __bf16* Rnf  = RW2 + (size_t)NREL * DIMN;           // normalized relations (fragment)
    __bf16* Wpk  = Rnf + FRAGR;                         // 5 packed weights
    __bf16* pWm1 = Wpk + 0 * (size_t)WPK_ELEMS;
    __bf16* pWl1 = Wpk + 1 * (size_t)WPK_ELEMS;
    __bf16* pWm2 = Wpk + 2 * (size_t)WPK_ELEMS;
    __bf16* pWl2 = Wpk + 3 * (size_t)WPK_ELEMS;
    __bf16* pWtg = Wpk + 4 * (size_t)WPK_ELEMS;
    int*  counts = (int*)(Wpk + 5 * (size_t)WPK_ELEMS);
    int2* sorted = (int2*)(counts + NNODES);
    int*  offs   = (int*)(sorted + NEDGES);
    int*  bsum   = offs + (NNODES + 1);
    int*  stmp   = bsum + 256;

    dim3 blk(256);
    const int GN = (NNODES + 63) / 64;      // 1563 blocks (4 frag-blocks each)
    dim3 ngrid32((NNODES * 32 + 255) / 256);   // 2 nodes/wave kernels
    dim3 rgrid32((NREL * 32 + 255) / 256);
    dim3 agrid((NNODES + 3) / 4);              // 1 node/wave kernels
    dim3 egrid((NEDGES + 255) / 256);
    const int NSB = (NNODES + SCAN_B - 1) / SCAN_B;

    pack_w<<<dim3((5 * KSTEPS * NB16 * 64 + 255) / 256), blk, 0, stream>>>(Wm1, Wl1, Wm2, Wl2, Wtg, Wpk);
    l2norm_frag<<<ngrid32, blk, 0, stream>>>(ent, A32, A16f, NNODES);
    l2norm_frag<<<rgrid32, blk, 0, stream>>>(relE, nullptr, Rnf, NREL);
    // relation GEMMs are time-invariant: hoist out of the loop
    gemm_bf<0><<<(NREL + 63) / 64, blk, 0, stream>>>(Rnf, pWm1, RW1, NREL, nullptr);
    gemm_bf<0><<<(NREL + 63) / 64, blk, 0, stream>>>(Rnf, pWm2, RW2, NREL, nullptr);

    for (int t = 0; t < 3; ++t) {
        const int* ed = edges + (size_t)t * NEDGES * 3;
        // ---- CSR build ----
        hipMemsetAsync(counts, 0, NNODES * sizeof(int), stream);
        edge_hist<<<egrid, blk, 0, stream>>>(ed, counts, NEDGES);
        scan1<<<NSB, SCAN_B, 0, stream>>>(counts, stmp, bsum, NNODES);
        scan2<<<1, 128, 0, stream>>>(bsum, NSB);
        scan3<<<NSB, SCAN_B, 0, stream>>>(stmp, bsum, offs, NNODES);
        hipMemsetAsync(counts, 0, NNODES * sizeof(int), stream);   // cursor
        edge_fill<<<egrid, blk, 0, stream>>>(ed, offs, counts, sorted, NEDGES);
        // ---- layer 1 ----
        gemm_bf<0><<<GN, blk, 0, stream>>>(A16f, pWm1, HW,   NNODES, nullptr);
        gemm_bf<0><<<GN, blk, 0, stream>>>(A16f, pWl1, Self, NNODES, nullptr);
        agg_combine<0><<<agrid, blk, 0, stream>>>(offs, sorted, HW, RW1, Self, Bbf, NNODES);
        // ---- layer 2 ----
        gemm_bf<0><<<GN, blk, 0, stream>>>(Bbf, pWm2, HW,   NNODES, nullptr);
        gemm_bf<0><<<GN, blk, 0, stream>>>(Bbf, pWl2, Self, NNODES, nullptr);
        agg_combine<1><<<agrid, blk, 0, stream>>>(offs, sorted, HW, RW2, Self, Bbf, NNODES);  // cur
        // ---- gate (sigmoid fused) -> HW ----
        gemm_bf<1><<<GN, blk, 0, stream>>>(A16f, pWtg, HW, NNODES, bias);
        // ---- h' = l2norm(gate*cur + (1-gate)*h) ----
        if (t == 2)
            gate_blend<<<ngrid32, blk, 0, stream>>>(HW, Bbf, A32, Dout, nullptr, NNODES);
        else
            gate_blend<<<ngrid32, blk, 0, stream>>>(HW, Bbf, A32, A32, A16f, NNODES);
    }
}

// Round 6
// 1061.822 us; speedup vs baseline: 3.6567x; 1.3658x over previous
//
#include <hip/hip_runtime.h>
#include <math.h>

#define DIMN   200
#define NNODES 100000
#define NREL   500
#define NEDGES 200000
#define KSTEPS 7            // K padded 200 -> 224 = 7*32
#define NB16   16           // N padded 200 -> 256
#define WPK_ELEMS (KSTEPS * NB16 * 64 * 8)   // 57344 bf16 per weight
#define SCAN_B 1024
#define NBN    6252         // node fragment blocks (16 rows each), covers 64-row grid
#define FRAG_STRIDE 3584    // elems per frag block = KSTEPS*512

typedef float  v4f  __attribute__((ext_vector_type(4)));
typedef __bf16 v8bf __attribute__((ext_vector_type(8)));

// A-fragment layout: element (row r in block nb, k = c*8+j) at
//   (nb*KSTEPS + c/4)*512 + (c%4)*128 + r*8 + j        (c = chunk 0..27)
__device__ __forceinline__ size_t frag_chunk(int nb, int c, int r) {
    return (size_t)(nb * KSTEPS + (c >> 2)) * 512 + (size_t)((c & 3) * 128 + r * 8);
}

// ---------------- prologue l2norm: fp32 rows -> bf16 row + optional bf16 frag ----------------
__launch_bounds__(256)
__global__ void l2norm_pro(const float* __restrict__ in, __bf16* __restrict__ outR,
                           __bf16* __restrict__ outF, int nrows)
{
    int idx  = blockIdx.x * 256 + threadIdx.x;
    int node = idx >> 5;
    int ch   = idx & 31;
    if (node >= nrows) return;
    float v[8] = {};
    if (ch < 25) {
        const float4* p = (const float4*)(in + (size_t)node * DIMN + ch * 8);
        float4 f0 = p[0], f1 = p[1];
        v[0]=f0.x; v[1]=f0.y; v[2]=f0.z; v[3]=f0.w;
        v[4]=f1.x; v[5]=f1.y; v[6]=f1.z; v[7]=f1.w;
    }
    float ss = 0.0f;
    #pragma unroll
    for (int k = 0; k < 8; ++k) ss += v[k] * v[k];
    #pragma unroll
    for (int off = 16; off; off >>= 1) ss += __shfl_xor(ss, off, 64);
    float s = 1.0f / fmaxf(sqrtf(ss), 1e-12f);
    #pragma unroll
    for (int k = 0; k < 8; ++k) v[k] *= s;
    if (ch < 25) {
        v8bf o;
        #pragma unroll
        for (int k = 0; k < 8; ++k) o[k] = (__bf16)v[k];
        *(v8bf*)(outR + (size_t)node * DIMN + ch * 8) = o;
    }
    if (outF && ch < 28) {
        v8bf o;
        #pragma unroll
        for (int k = 0; k < 8; ++k) o[k] = (ch < 25) ? (__bf16)v[k] : (__bf16)0.0f;
        *(v8bf*)(outF + frag_chunk(node >> 4, ch, node & 15)) = o;
    }
}

// ---------------- CSR build ----------------
__launch_bounds__(256)
__global__ void edge_hist(const int* __restrict__ edges, int* __restrict__ counts, int nedges)
{
    int e = blockIdx.x * 256 + threadIdx.x;
    if (e < nedges) atomicAdd(&counts[edges[e * 3 + 2]], 1);
}

__launch_bounds__(SCAN_B)
__global__ void scan1(const int* __restrict__ counts, int* __restrict__ tmp,
                      int* __restrict__ bsum, int n)
{
    __shared__ int sh[SCAN_B];
    int i = blockIdx.x * SCAN_B + threadIdx.x;
    int v = (i < n) ? counts[i] : 0;
    sh[threadIdx.x] = v;
    __syncthreads();
    for (int off = 1; off < SCAN_B; off <<= 1) {
        int t = (threadIdx.x >= off) ? sh[threadIdx.x - off] : 0;
        __syncthreads();
        sh[threadIdx.x] += t;
        __syncthreads();
    }
    if (i < n) tmp[i] = sh[threadIdx.x];
    if (threadIdx.x == SCAN_B - 1) bsum[blockIdx.x] = sh[threadIdx.x];
}

__launch_bounds__(128)
__global__ void scan2(int* __restrict__ bsum, int nb)
{
    __shared__ int sh[128];
    int v = (threadIdx.x < nb) ? bsum[threadIdx.x] : 0;
    sh[threadIdx.x] = v;
    __syncthreads();
    for (int off = 1; off < 128; off <<= 1) {
        int t = (threadIdx.x >= off) ? sh[threadIdx.x - off] : 0;
        __syncthreads();
        sh[threadIdx.x] += t;
        __syncthreads();
    }
    if (threadIdx.x < nb) bsum[threadIdx.x] = sh[threadIdx.x] - v;
}

__launch_bounds__(SCAN_B)
__global__ void scan3(const int* __restrict__ tmp, const int* __restrict__ bsum,
                      int* __restrict__ offs, int n)
{
    int i = blockIdx.x * SCAN_B + threadIdx.x;
    if (i < n) offs[i + 1] = tmp[i] + bsum[blockIdx.x];
    if (i == 0) offs[0] = 0;
}

__launch_bounds__(256)
__global__ void edge_fill(const int* __restrict__ edges, const int* __restrict__ offs,
                          int* __restrict__ cursor, int2* __restrict__ sorted, int nedges)
{
    int e = blockIdx.x * 256 + threadIdx.x;
    if (e >= nedges) return;
    int s = edges[e * 3 + 0];
    int r = edges[e * 3 + 1];
    int d = edges[e * 3 + 2];
    int p = offs[d] + atomicAdd(&cursor[d], 1);
    sorted[p] = make_int2(s, r);
}

// ---------------- aggregate in h-space: S = segsum(x[src] + r[rel]) / max(deg,1) ----------------
// one wave per node; lanes 0..24 gather x chunks, lanes 32..56 gather r chunks; write S in frag layout
__launch_bounds__(256)
__global__ void agg_S(const int* __restrict__ offs, const int2* __restrict__ sorted,
                      const __bf16* __restrict__ XR, const __bf16* __restrict__ RnR,
                      __bf16* __restrict__ SF, int nnodes)
{
    int wave = (int)((blockIdx.x * blockDim.x + threadIdx.x) >> 6);
    int lane = threadIdx.x & 63;
    if (wave >= nnodes) return;
    int beg = offs[wave], end = offs[wave + 1];
    int ch = lane & 31;
    bool act = ch < 25;

    float acc[8] = {};
    for (int e = beg; e < end; ++e) {
        int2 sr = sorted[e];
        const __bf16* base = (lane < 32) ? (XR + (size_t)sr.x * DIMN)
                                         : (RnR + (size_t)sr.y * DIMN);
        v8bf v = {};
        if (act) v = *(const v8bf*)(base + ch * 8);
        #pragma unroll
        for (int k = 0; k < 8; ++k) acc[k] += (float)v[k];
    }
    #pragma unroll
    for (int k = 0; k < 8; ++k) acc[k] += __shfl_xor(acc[k], 32, 64);

    float rdeg = 1.0f / fmaxf((float)(end - beg), 1.0f);
    if (lane < 32 && ch < 28) {
        v8bf o;
        #pragma unroll
        for (int k = 0; k < 8; ++k) o[k] = act ? (__bf16)(acc[k] * rdeg) : (__bf16)0.0f;
        *(v8bf*)(SF + frag_chunk(wave >> 4, ch, wave & 15)) = o;
    }
}

// ---------------- weight pack: fp32 W[200x200] -> bf16 MFMA-B-fragment-linear ----------------
__launch_bounds__(256)
__global__ void pack_w(const float* __restrict__ W0, const float* __restrict__ W1,
                       const float* __restrict__ W2, const float* __restrict__ W3,
                       const float* __restrict__ W4, __bf16* __restrict__ out)
{
    int id = blockIdx.x * 256 + threadIdx.x;
    const int nchunk = KSTEPS * NB16 * 64;        // 7168
    if (id >= 5 * nchunk) return;
    int wi = id / nchunk;
    int c  = id % nchunk;
    const float* W = wi == 0 ? W0 : wi == 1 ? W1 : wi == 2 ? W2 : wi == 3 ? W3 : W4;
    int s    = c >> 10;
    int nb   = (c & 1023) >> 6;
    int lane = c & 63;
    int kbase = s * 32 + (lane >> 4) * 8;
    int n     = nb * 16 + (lane & 15);
    __bf16* dst = out + (size_t)wi * WPK_ELEMS + (size_t)c * 8;
    #pragma unroll
    for (int j = 0; j < 8; ++j) {
        int k = kbase + j;
        float v = (k < DIMN && n < DIMN) ? W[k * DIMN + n] : 0.0f;
        dst[j] = (__bf16)v;
    }
}

// ---------------- G1: Out = A1@W1 + A2@W2 ; BM=64 ; writes row-major + frag via LDS ----------------
__launch_bounds__(256)
__global__ void gemm_dual(const __bf16* __restrict__ A1, const __bf16* __restrict__ W1,
                          const __bf16* __restrict__ A2, const __bf16* __restrict__ W2,
                          __bf16* __restrict__ OutR, __bf16* __restrict__ OutF, int M)
{
    const int tid  = threadIdx.x;
    const int w    = tid >> 6;
    const int lane = tid & 63;
    const int rlo  = lane & 15;
    const int g    = lane >> 4;
    const int nb0  = blockIdx.x * 4;
    const int bm   = blockIdx.x * 64;

    __shared__ __bf16 T[64][264];

    v4f acc[4][4];
    #pragma unroll
    for (int mi = 0; mi < 4; ++mi)
        #pragma unroll
        for (int ni = 0; ni < 4; ++ni)
            acc[mi][ni] = (v4f){0.f, 0.f, 0.f, 0.f};

    const __bf16* w1b = W1 + (size_t)(w * 4 * 64 + lane) * 8;
    const __bf16* w2b = W2 + (size_t)(w * 4 * 64 + lane) * 8;

    for (int s = 0; s < KSTEPS; ++s) {
        v8bf b1[4], b2[4];
        #pragma unroll
        for (int ni = 0; ni < 4; ++ni) {
            b1[ni] = *(const v8bf*)(w1b + ((size_t)s * NB16 * 64 + ni * 64) * 8);
            b2[ni] = *(const v8bf*)(w2b + ((size_t)s * NB16 * 64 + ni * 64) * 8);
        }
        #pragma unroll
        for (int mi = 0; mi < 4; ++mi) {
            size_t aoff = (size_t)((nb0 + mi) * KSTEPS + s) * 512 + lane * 8;
            v8bf a1 = *(const v8bf*)(A1 + aoff);
            v8bf a2 = *(const v8bf*)(A2 + aoff);
            #pragma unroll
            for (int ni = 0; ni < 4; ++ni)
                acc[mi][ni] = __builtin_amdgcn_mfma_f32_16x16x32_bf16(a1, b1[ni], acc[mi][ni], 0, 0, 0);
            #pragma unroll
            for (int ni = 0; ni < 4; ++ni)
                acc[mi][ni] = __builtin_amdgcn_mfma_f32_16x16x32_bf16(a2, b2[ni], acc[mi][ni], 0, 0, 0);
        }
    }

    // D -> LDS tile (row_local = mi*16 + g*4 + reg, col = w*64 + ni*16 + rlo)
    #pragma unroll
    for (int mi = 0; mi < 4; ++mi)
        #pragma unroll
        for (int reg = 0; reg < 4; ++reg)
            #pragma unroll
            for (int ni = 0; ni < 4; ++ni)
                T[mi * 16 + g * 4 + reg][w * 64 + ni * 16 + rlo] = (__bf16)acc[mi][ni][reg];
    __syncthreads();

    // frag emit: 4 nb * 7 s * 64 slots = 1792
    #pragma unroll
    for (int j = 0; j < 7; ++j) {
        int it = tid + j * 256;
        int slot = it & 63;
        int q = it >> 6;          // 0..27
        int s = q % 7, nb = q / 7;
        *(v8bf*)(OutF + (size_t)((nb0 + nb) * KSTEPS + s) * 512 + slot * 8) =
            *(const v8bf*)&T[nb * 16 + (slot & 15)][s * 32 + (slot >> 4) * 8];
    }
    // row emit: 64 rows * 25 chunks = 1600
    #pragma unroll
    for (int j = 0; j < 7; ++j) {
        int it = tid + j * 256;
        if (it < 1600) {
            int row = it / 25, ch = it - row * 25;
            int gr = bm + row;
            if (gr < M)
                *(v8bf*)(OutR + (size_t)gr * DIMN + ch * 8) = *(const v8bf*)&T[row][ch * 8];
        }
    }
}

// ---------------- G2 mega: cur = l2norm(A1@W1 + A2@W2); gate = sigmoid(A3@W3 + bias);
//                  h' = l2norm(gate*cur + (1-gate)*h)  (in-place h update, or fp32 Dout at final step)
__launch_bounds__(256)
__global__ void gemm_mega(const __bf16* __restrict__ A1, const __bf16* __restrict__ W1,
                          const __bf16* __restrict__ A2, const __bf16* __restrict__ W2,
                          const __bf16* __restrict__ A3, const __bf16* __restrict__ W3,
                          const float* __restrict__ Bias,
                          __bf16* __restrict__ HR, __bf16* __restrict__ HF,
                          float* __restrict__ DoutF, int M, int finalStep)
{
    const int tid  = threadIdx.x;
    const int w    = tid >> 6;
    const int lane = tid & 63;
    const int rlo  = lane & 15;
    const int g    = lane >> 4;
    const int nb0  = blockIdx.x * 2;
    const int bm   = blockIdx.x * 32;

    __shared__ __bf16 T[32][264];
    __shared__ __bf16 Th[32][264];
    __shared__ float  rsq1[32][4];
    __shared__ float  rsq2[32][4];

    v4f acc1[2][4], acc2[2][4];
    #pragma unroll
    for (int mi = 0; mi < 2; ++mi)
        #pragma unroll
        for (int ni = 0; ni < 4; ++ni) {
            acc1[mi][ni] = (v4f){0.f, 0.f, 0.f, 0.f};
            acc2[mi][ni] = (v4f){0.f, 0.f, 0.f, 0.f};
        }

    const __bf16* w1b = W1 + (size_t)(w * 4 * 64 + lane) * 8;
    const __bf16* w2b = W2 + (size_t)(w * 4 * 64 + lane) * 8;
    const __bf16* w3b = W3 + (size_t)(w * 4 * 64 + lane) * 8;

    for (int s = 0; s < KSTEPS; ++s) {
        v8bf b1[4], b2[4], b3[4];
        #pragma unroll
        for (int ni = 0; ni < 4; ++ni) {
            size_t bo = ((size_t)s * NB16 * 64 + ni * 64) * 8;
            b1[ni] = *(const v8bf*)(w1b + bo);
            b2[ni] = *(const v8bf*)(w2b + bo);
            b3[ni] = *(const v8bf*)(w3b + bo);
        }
        #pragma unroll
        for (int mi = 0; mi < 2; ++mi) {
            size_t aoff = (size_t)((nb0 + mi) * KSTEPS + s) * 512 + lane * 8;
            v8bf a1 = *(const v8bf*)(A1 + aoff);
            v8bf a2 = *(const v8bf*)(A2 + aoff);
            v8bf a3 = *(const v8bf*)(A3 + aoff);
            #pragma unroll
            for (int ni = 0; ni < 4; ++ni)
                acc1[mi][ni] = __builtin_amdgcn_mfma_f32_16x16x32_bf16(a1, b1[ni], acc1[mi][ni], 0, 0, 0);
            #pragma unroll
            for (int ni = 0; ni < 4; ++ni)
                acc1[mi][ni] = __builtin_amdgcn_mfma_f32_16x16x32_bf16(a2, b2[ni], acc1[mi][ni], 0, 0, 0);
            #pragma unroll
            for (int ni = 0; ni < 4; ++ni)
                acc2[mi][ni] = __builtin_amdgcn_mfma_f32_16x16x32_bf16(a3, b3[ni], acc2[mi][ni], 0, 0, 0);
        }
    }

    // cur row sums-of-squares
    #pragma unroll
    for (int mi = 0; mi < 2; ++mi)
        #pragma unroll
        for (int reg = 0; reg < 4; ++reg) {
            float ss = 0.0f;
            #pragma unroll
            for (int ni = 0; ni < 4; ++ni) ss += acc1[mi][ni][reg] * acc1[mi][ni][reg];
            ss += __shfl_xor(ss, 1, 64);
            ss += __shfl_xor(ss, 2, 64);
            ss += __shfl_xor(ss, 4, 64);
            ss += __shfl_xor(ss, 8, 64);
            if (rlo == 0) rsq1[mi * 16 + g * 4 + reg][w] = ss;
        }
    // stage h rows into Th
    #pragma unroll
    for (int j = 0; j < 4; ++j) {
        int it = tid + j * 256;
        if (it < 800) {
            int row = it / 25, ch = it - row * 25;
            int gr = bm + row;
            v8bf hv = {};
            if (gr < M) hv = *(const v8bf*)(HR + (size_t)gr * DIMN + ch * 8);
            *(v8bf*)&Th[row][ch * 8] = hv;
        }
    }
    __syncthreads();

    // blend: v = gate*cur + (1-gate)*h  (store into acc1), second row reduce
    #pragma unroll
    for (int mi = 0; mi < 2; ++mi)
        #pragma unroll
        for (int reg = 0; reg < 4; ++reg) {
            int rl = mi * 16 + g * 4 + reg;
            float tot = rsq1[rl][0] + rsq1[rl][1] + rsq1[rl][2] + rsq1[rl][3];
            float sc1 = 1.0f / fmaxf(sqrtf(tot), 1e-12f);
            float ss = 0.0f;
            #pragma unroll
            for (int ni = 0; ni < 4; ++ni) {
                int c = w * 64 + ni * 16 + rlo;
                float v = 0.0f;
                if (c < DIMN) {
                    float cur = acc1[mi][ni][reg] * sc1;
                    float gg  = 1.0f / (1.0f + __expf(-(acc2[mi][ni][reg] + Bias[c])));
                    float hh  = (float)Th[rl][c];
                    v = gg * cur + (1.0f - gg) * hh;
                }
                acc1[mi][ni][reg] = v;
                ss += v * v;
            }
            ss += __shfl_xor(ss, 1, 64);
            ss += __shfl_xor(ss, 2, 64);
            ss += __shfl_xor(ss, 4, 64);
            ss += __shfl_xor(ss, 8, 64);
            if (rlo == 0) rsq2[rl][w] = ss;
        }
    __syncthreads();

    // final scale -> T
    #pragma unroll
    for (int mi = 0; mi < 2; ++mi)
        #pragma unroll
        for (int reg = 0; reg < 4; ++reg) {
            int rl = mi * 16 + g * 4 + reg;
            float tot = rsq2[rl][0] + rsq2[rl][1] + rsq2[rl][2] + rsq2[rl][3];
            float sc2 = 1.0f / fmaxf(sqrtf(tot), 1e-12f);
            #pragma unroll
            for (int ni = 0; ni < 4; ++ni) {
                int c = w * 64 + ni * 16 + rlo;
                T[rl][c] = (__bf16)(acc1[mi][ni][reg] * sc2);
            }
        }
    __syncthreads();

    if (!finalStep) {
        // h' rows
        #pragma unroll
        for (int j = 0; j < 4; ++j) {
            int it = tid + j * 256;
            if (it < 800) {
                int row = it / 25, ch = it - row * 25;
                int gr = bm + row;
                if (gr < M)
                    *(v8bf*)(HR + (size_t)gr * DIMN + ch * 8) = *(const v8bf*)&T[row][ch * 8];
            }
        }
        // h' frag: 2 nb * 7 s * 64 slots = 896
        #pragma unroll
        for (int j = 0; j < 4; ++j) {
            int it = tid + j * 256;
            if (it < 896) {
                int slot = it & 63;
                int q = it >> 6;          // 0..13
                int s = q % 7, nb = q / 7;
                *(v8bf*)(HF + (size_t)((nb0 + nb) * KSTEPS + s) * 512 + slot * 8) =
                    *(const v8bf*)&T[nb * 16 + (slot & 15)][s * 32 + (slot >> 4) * 8];
            }
        }
    } else {
        // fp32 output rows
        #pragma unroll
        for (int j = 0; j < 4; ++j) {
            int it = tid + j * 256;
            if (it < 800) {
                int row = it / 25, ch = it - row * 25;
                int gr = bm + row;
                if (gr < M) {
                    v8bf o = *(const v8bf*)&T[row][ch * 8];
                    float4* q0 = (float4*)(DoutF + (size_t)gr * DIMN + ch * 8);
                    q0[0] = make_float4((float)o[0], (float)o[1], (float)o[2], (float)o[3]);
                    q0[1] = make_float4((float)o[4], (float)o[5], (float)o[6], (float)o[7]);
                }
            }
        }
    }
}

extern "C" void kernel_launch(void* const* d_in, const int* in_sizes, int n_in,
                              void* d_out, int out_size, void* d_ws, size_t ws_size,
                              hipStream_t stream)
{
    const int*   edges = (const int*)  d_in[0];
    const float* ent   = (const float*)d_in[1];
    const float* relE  = (const float*)d_in[2];
    const float* Wm1   = (const float*)d_in[3];
    const float* Wl1   = (const float*)d_in[4];
    const float* Wm2   = (const float*)d_in[5];
    const float* Wl2   = (const float*)d_in[6];
    const float* Wtg   = (const float*)d_in[7];
    const float* bias  = (const float*)d_in[8];
    float* Dout = (float*)d_out;

    const size_t NM    = (size_t)NNODES * DIMN;
    const size_t FRAGN = (size_t)NBN * FRAG_STRIDE;

    __bf16* hR   = (__bf16*)d_ws;                      // h row-major (gather + mega-epilogue)
    __bf16* hF   = hR + NM;                            // h fragment (GEMM-A)
    __bf16* SF   = hF + FRAGN;                         // S1/S2 fragment
    __bf16* BR   = SF + FRAGN;                         // layer-1 out rows (gather)
    __bf16* BF   = BR + NM;                            // layer-1 out fragment
    __bf16* RnR  = BF + FRAGN;                         // normalized relations rows
    __bf16* Wpk  = RnR + (size_t)NREL * DIMN;          // 5 packed weights
    __bf16* pWm1 = Wpk + 0 * (size_t)WPK_ELEMS;
    __bf16* pWl1 = Wpk + 1 * (size_t)WPK_ELEMS;
    __bf16* pWm2 = Wpk + 2 * (size_t)WPK_ELEMS;
    __bf16* pWl2 = Wpk + 3 * (size_t)WPK_ELEMS;
    __bf16* pWtg = Wpk + 4 * (size_t)WPK_ELEMS;
    int*  counts = (int*)(Wpk + 5 * (size_t)WPK_ELEMS);
    int2* sorted = (int2*)(counts + NNODES);
    int*  offs   = (int*)(sorted + NEDGES);
    int*  bsum   = offs + (NNODES + 1);
    int*  stmp   = bsum + 256;

    dim3 blk(256);
    const int G1 = (NNODES + 63) / 64;      // 1563
    const int G2 = (NNODES + 31) / 32;      // 3125
    dim3 ngrid32((NNODES * 32 + 255) / 256);
    dim3 rgrid32((NREL * 32 + 255) / 256);
    dim3 agrid((NNODES + 3) / 4);
    dim3 egrid((NEDGES + 255) / 256);
    const int NSB = (NNODES + SCAN_B - 1) / SCAN_B;

    pack_w<<<dim3((5 * KSTEPS * NB16 * 64 + 255) / 256), blk, 0, stream>>>(Wm1, Wl1, Wm2, Wl2, Wtg, Wpk);
    l2norm_pro<<<ngrid32, blk, 0, stream>>>(ent, hR, hF, NNODES);
    l2norm_pro<<<rgrid32, blk, 0, stream>>>(relE, RnR, nullptr, NREL);

    for (int t = 0; t < 3; ++t) {
        const int* ed = edges + (size_t)t * NEDGES * 3;
        // ---- CSR build ----
        hipMemsetAsync(counts, 0, NNODES * sizeof(int), stream);
        edge_hist<<<egrid, blk, 0, stream>>>(ed, counts, NEDGES);
        scan1<<<NSB, SCAN_B, 0, stream>>>(counts, stmp, bsum, NNODES);
        scan2<<<1, 128, 0, stream>>>(bsum, NSB);
        scan3<<<NSB, SCAN_B, 0, stream>>>(stmp, bsum, offs, NNODES);
        hipMemsetAsync(counts, 0, NNODES * sizeof(int), stream);   // cursor
        edge_fill<<<egrid, blk, 0, stream>>>(ed, offs, counts, sorted, NEDGES);
        // ---- layer 1 (linearity: aggregate in h-space, then fused dual-stream GEMM) ----
        agg_S<<<agrid, blk, 0, stream>>>(offs, sorted, hR, RnR, SF, NNODES);
        gemm_dual<<<G1, blk, 0, stream>>>(SF, pWm1, hF, pWl1, BR, BF, NNODES);
        // ---- layer 2 + gate + blend + norms (mega) ----
        agg_S<<<agrid, blk, 0, stream>>>(offs, sorted, BR, RnR, SF, NNODES);
        gemm_mega<<<G2, blk, 0, stream>>>(SF, pWm2, BF, pWl2, hF, pWtg, bias,
                                          hR, hF, Dout, NNODES, (t == 2) ? 1 : 0);
    }
}